// Round 1
// baseline (188.003 us; speedup 1.0000x reference)
//
#include <hip/hip_runtime.h>
#include <stdint.h>

typedef __attribute__((ext_vector_type(8))) short short8;
typedef __attribute__((ext_vector_type(4))) float f32x4;

static __device__ __forceinline__ unsigned short f2bf(float f) {
  unsigned int u = __float_as_uint(f);
  u += 0x7FFFu + ((u >> 16) & 1u);
  return (unsigned short)(u >> 16);
}
static __device__ __forceinline__ float bf2f(unsigned short h) {
  return __uint_as_float(((unsigned int)h) << 16);
}

#define GLD16(gp, lp) __builtin_amdgcn_global_load_lds( \
    (__attribute__((address_space(1))) void*)(gp), \
    (__attribute__((address_space(3))) void*)(lp), 16, 0, 0)

// ---------------- fp32 -> bf16 elementwise (8 per thread) ----------------
__global__ __launch_bounds__(256) void k_cvt(const float* __restrict__ in,
                                             unsigned short* __restrict__ out,
                                             int n8) {
  int i = blockIdx.x * 256 + threadIdx.x;
  if (i >= n8) return;
  const float4* p = (const float4*)in + (long)i * 2;
  float4 a = p[0], b = p[1];
  short8 v;
  v[0] = (short)f2bf(a.x); v[1] = (short)f2bf(a.y);
  v[2] = (short)f2bf(a.z); v[3] = (short)f2bf(a.w);
  v[4] = (short)f2bf(b.x); v[5] = (short)f2bf(b.y);
  v[6] = (short)f2bf(b.z); v[7] = (short)f2bf(b.w);
  *(short8*)(out + (long)i * 8) = v;
}

// ---------------- fp32 [R][C] -> bf16 [C][R] transpose -------------------
__global__ __launch_bounds__(256) void k_tpose(const float* __restrict__ in,
                                               unsigned short* __restrict__ out,
                                               int R, int C) {
  __shared__ float tile[32][33];
  int tx = threadIdx.x, ty = threadIdx.y;
  int c0 = blockIdx.x * 32, r0 = blockIdx.y * 32;
#pragma unroll
  for (int i = 0; i < 4; i++)
    tile[ty + i * 8][tx] = in[(long)(r0 + ty + i * 8) * C + c0 + tx];
  __syncthreads();
#pragma unroll
  for (int i = 0; i < 4; i++)
    out[(long)(c0 + ty + i * 8) * R + r0 + tx] = f2bf(tile[tx][ty + i * 8]);
}

// ---------------- pack bq|bk|bv into one [1536] buffer -------------------
__global__ void k_packb(const float* __restrict__ a, const float* __restrict__ b,
                        const float* __restrict__ c, float* __restrict__ o) {
  int i = blockIdx.x * 256 + threadIdx.x;
  if (i < 512) o[i] = a[i];
  else if (i < 1024) o[i] = b[i - 512];
  else if (i < 1536) o[i] = c[i - 1024];
}

// ---------------- bf16 MFMA GEMM: C[M,N] = A[M,K] @ Bt[N,K]^T + bias ------
// 128x128 tile, BK=32, 4 waves (2x2), each wave 4x4 fragments of 16x16x32.
// EPI: 0 = bias, 1 = bias + relu. Output bf16.
template <int EPI>
__global__ __launch_bounds__(256) void k_gemm(const unsigned short* __restrict__ A,
                                              const unsigned short* __restrict__ Bt,
                                              const float* __restrict__ bias,
                                              unsigned short* __restrict__ C,
                                              int M, int N, int K) {
  __shared__ unsigned short As[128 * 32];
  __shared__ unsigned short Bs[128 * 32];
  const int t = threadIdx.x;
  const int lane = t & 63;
  const int w = t >> 6;
  const int wr = w >> 1, wc = w & 1;
  const int m0 = blockIdx.y * 128;
  const int n0 = blockIdx.x * 128;

  f32x4 acc[4][4];
#pragma unroll
  for (int mi = 0; mi < 4; mi++)
#pragma unroll
    for (int ni = 0; ni < 4; ni++) {
      f32x4 z = {0.f, 0.f, 0.f, 0.f};
      acc[mi][ni] = z;
    }

  // staging: tile [128][32] bf16 = 512 x 16B chunks; each thread 2 chunks
  const int c0 = t;
  const int c1 = t + 256;
  const int arow0 = c0 >> 2, acol0 = (c0 & 3) * 8;
  const int arow1 = c1 >> 2, acol1 = (c1 & 3) * 8;

  for (int k0 = 0; k0 < K; k0 += 32) {
    GLD16(A + (long)(m0 + arow0) * K + k0 + acol0, As + (long)c0 * 8);
    GLD16(A + (long)(m0 + arow1) * K + k0 + acol1, As + (long)c1 * 8);
    GLD16(Bt + (long)(n0 + arow0) * K + k0 + acol0, Bs + (long)c0 * 8);
    GLD16(Bt + (long)(n0 + arow1) * K + k0 + acol1, Bs + (long)c1 * 8);
    __syncthreads();

    short8 af[4], bf[4];
#pragma unroll
    for (int mi = 0; mi < 4; mi++)
      af[mi] = *(const short8*)&As[(wr * 64 + mi * 16 + (lane & 15)) * 32 + (lane >> 4) * 8];
#pragma unroll
    for (int ni = 0; ni < 4; ni++)
      bf[ni] = *(const short8*)&Bs[(wc * 64 + ni * 16 + (lane & 15)) * 32 + (lane >> 4) * 8];
#pragma unroll
    for (int mi = 0; mi < 4; mi++)
#pragma unroll
      for (int ni = 0; ni < 4; ni++)
        acc[mi][ni] = __builtin_amdgcn_mfma_f32_16x16x32_bf16(af[mi], bf[ni], acc[mi][ni], 0, 0, 0);
    __syncthreads();
  }

  const int lr = (lane >> 4) * 4;
  const int lc = lane & 15;
#pragma unroll
  for (int mi = 0; mi < 4; mi++) {
#pragma unroll
    for (int ni = 0; ni < 4; ni++) {
      const int col = n0 + wc * 64 + ni * 16 + lc;
      const float bv = bias[col];
#pragma unroll
      for (int r = 0; r < 4; r++) {
        const int row = m0 + wr * 64 + mi * 16 + lr + r;
        float v = acc[mi][ni][r] + bv;
        if (EPI == 1) v = fmaxf(v, 0.f);
        C[(long)row * N + col] = f2bf(v);
      }
    }
  }
}

// ---------------- attention: wave per row, K=32 neighbors ------------------
// qkv: [8192][1536] bf16 (q | k | v). att: [8192][512] bf16 (pre-Wo).
__global__ __launch_bounds__(256) void k_attn(const unsigned short* __restrict__ qkv,
                                              const float* __restrict__ adj,
                                              const int* __restrict__ inxs,
                                              unsigned short* __restrict__ att) {
  const int lane = threadIdx.x & 63;
  const int w = threadIdx.x >> 6;
  const int row = blockIdx.x * 4 + w;  // 0..8191
  const int b = row >> 11;
  const int n = row & 2047;

  const unsigned short* qp = qkv + (long)row * 1536 + lane * 8;
  short8 qv = *(const short8*)qp;
  float qf[8];
#pragma unroll
  for (int j = 0; j < 8; j++) qf[j] = bf2f((unsigned short)qv[j]);

  const int* ix = inxs + ((long)b * 2048 + n) * 32;
  const float* adjrow = adj + ((long)b * 2048 + n) * 2048;

  float sc[32];
#pragma unroll
  for (int kk = 0; kk < 32; kk++) {
    const int idx = ix[kk];
    const unsigned short* kp = qkv + ((long)(b * 2048 + idx)) * 1536 + 512 + lane * 8;
    short8 kv = *(const short8*)kp;
    float d = 0.f;
#pragma unroll
    for (int j = 0; j < 8; j++) d += qf[j] * bf2f((unsigned short)kv[j]);
#pragma unroll
    for (int m = 32; m >= 1; m >>= 1) d += __shfl_xor(d, m, 64);
    const float a = adjrow[idx];
    sc[kk] = d * 0.044194173824159216f + (a > 0.f ? 0.f : -1e22f);
  }

  float mx = sc[0];
#pragma unroll
  for (int kk = 1; kk < 32; kk++) mx = fmaxf(mx, sc[kk]);
  float ssum = 0.f;
#pragma unroll
  for (int kk = 0; kk < 32; kk++) {
    sc[kk] = __expf(sc[kk] - mx);
    ssum += sc[kk];
  }
  const float inv = 1.f / ssum;

  float o[8] = {0, 0, 0, 0, 0, 0, 0, 0};
#pragma unroll
  for (int kk = 0; kk < 32; kk++) {
    const int idx = ix[kk];
    const unsigned short* vp = qkv + ((long)(b * 2048 + idx)) * 1536 + 1024 + lane * 8;
    short8 vv = *(const short8*)vp;
    const float p = sc[kk] * inv;
#pragma unroll
    for (int j = 0; j < 8; j++) o[j] += p * bf2f((unsigned short)vv[j]);
  }

  short8 ov;
#pragma unroll
  for (int j = 0; j < 8; j++) ov[j] = (short)f2bf(o[j]);
  *(short8*)(att + (long)row * 512 + lane * 8) = ov;
}

// ---------------- LN1: y = LN(x_f32 + o_bf16) * g + beta, out bf16 --------
__global__ __launch_bounds__(256) void k_ln1(const float* __restrict__ x,
                                             const unsigned short* __restrict__ o,
                                             const float* __restrict__ g,
                                             const float* __restrict__ beta,
                                             unsigned short* __restrict__ y) {
  const int lane = threadIdx.x & 63;
  const int w = threadIdx.x >> 6;
  const long row = (long)blockIdx.x * 4 + w;
  const float4* xp = (const float4*)(x + row * 512 + lane * 8);
  float4 x0 = xp[0], x1 = xp[1];
  short8 ov = *(const short8*)(o + row * 512 + lane * 8);
  float tv[8] = {x0.x, x0.y, x0.z, x0.w, x1.x, x1.y, x1.z, x1.w};
  float s = 0.f, s2 = 0.f;
#pragma unroll
  for (int j = 0; j < 8; j++) {
    tv[j] += bf2f((unsigned short)ov[j]);
    s += tv[j];
    s2 += tv[j] * tv[j];
  }
#pragma unroll
  for (int m = 32; m >= 1; m >>= 1) {
    s += __shfl_xor(s, m, 64);
    s2 += __shfl_xor(s2, m, 64);
  }
  const float mean = s * (1.f / 512.f);
  const float var = s2 * (1.f / 512.f) - mean * mean;
  const float r = rsqrtf(var + 1e-5f);
  const float4* gp = (const float4*)(g + lane * 8);
  const float4* bp = (const float4*)(beta + lane * 8);
  float4 g0 = gp[0], g1v = gp[1], b0 = bp[0], b1 = bp[1];
  float gg[8] = {g0.x, g0.y, g0.z, g0.w, g1v.x, g1v.y, g1v.z, g1v.w};
  float bb[8] = {b0.x, b0.y, b0.z, b0.w, b1.x, b1.y, b1.z, b1.w};
  short8 yv;
#pragma unroll
  for (int j = 0; j < 8; j++) yv[j] = (short)f2bf((tv[j] - mean) * r * gg[j] + bb[j]);
  *(short8*)(y + row * 512 + lane * 8) = yv;
}

// ---------------- LN2: out_f32 = LN(y_bf16 + f_bf16) * g + beta -----------
__global__ __launch_bounds__(256) void k_ln2(const unsigned short* __restrict__ y,
                                             const unsigned short* __restrict__ f,
                                             const float* __restrict__ g,
                                             const float* __restrict__ beta,
                                             float* __restrict__ out) {
  const int lane = threadIdx.x & 63;
  const int w = threadIdx.x >> 6;
  const long row = (long)blockIdx.x * 4 + w;
  short8 yv = *(const short8*)(y + row * 512 + lane * 8);
  short8 fv = *(const short8*)(f + row * 512 + lane * 8);
  float tv[8];
  float s = 0.f, s2 = 0.f;
#pragma unroll
  for (int j = 0; j < 8; j++) {
    tv[j] = bf2f((unsigned short)yv[j]) + bf2f((unsigned short)fv[j]);
    s += tv[j];
    s2 += tv[j] * tv[j];
  }
#pragma unroll
  for (int m = 32; m >= 1; m >>= 1) {
    s += __shfl_xor(s, m, 64);
    s2 += __shfl_xor(s2, m, 64);
  }
  const float mean = s * (1.f / 512.f);
  const float var = s2 * (1.f / 512.f) - mean * mean;
  const float r = rsqrtf(var + 1e-5f);
  const float4* gp = (const float4*)(g + lane * 8);
  const float4* bp = (const float4*)(beta + lane * 8);
  float4 g0 = gp[0], g1v = gp[1], b0 = bp[0], b1 = bp[1];
  float gg[8] = {g0.x, g0.y, g0.z, g0.w, g1v.x, g1v.y, g1v.z, g1v.w};
  float bb[8] = {b0.x, b0.y, b0.z, b0.w, b1.x, b1.y, b1.z, b1.w};
  float ovv[8];
#pragma unroll
  for (int j = 0; j < 8; j++) ovv[j] = (tv[j] - mean) * r * gg[j] + bb[j];
  float4* op = (float4*)(out + row * 512 + lane * 8);
  float4 o0 = {ovv[0], ovv[1], ovv[2], ovv[3]};
  float4 o1 = {ovv[4], ovv[5], ovv[6], ovv[7]};
  op[0] = o0;
  op[1] = o1;
}

extern "C" void kernel_launch(void* const* d_in, const int* in_sizes, int n_in,
                              void* d_out, int out_size, void* d_ws, size_t ws_size,
                              hipStream_t stream) {
  const float* x   = (const float*)d_in[0];
  const float* adj = (const float*)d_in[1];
  const int*   inx = (const int*)d_in[2];
  const float* Wq  = (const float*)d_in[3];
  const float* bq  = (const float*)d_in[4];
  const float* Wk  = (const float*)d_in[5];
  const float* bk  = (const float*)d_in[6];
  const float* Wv  = (const float*)d_in[7];
  const float* bv  = (const float*)d_in[8];
  const float* Wo  = (const float*)d_in[9];
  const float* bo  = (const float*)d_in[10];
  const float* g1  = (const float*)d_in[11];
  const float* be1 = (const float*)d_in[12];
  const float* W1  = (const float*)d_in[13];
  const float* bf1 = (const float*)d_in[14];
  const float* W2  = (const float*)d_in[15];
  const float* bf2 = (const float*)d_in[16];
  const float* g2  = (const float*)d_in[17];
  const float* be2 = (const float*)d_in[18];

  // workspace layout (bf16 elements unless noted); aliased reuse is
  // stream-ordered-safe: att<-xb (xb dead after G1), h<-qkv (dead after attn),
  // f<-oproj (dead after LN1). Total ~54 MB.
  unsigned short* xb    = (unsigned short*)d_ws;        // 8192*512
  unsigned short* wqkvt = xb + 4194304;                 // 1536*512 (B^T)
  unsigned short* wot   = wqkvt + 786432;               // 512*512
  unsigned short* w1t   = wot + 262144;                 // 768*512
  unsigned short* w2t   = w1t + 393216;                 // 512*768
  unsigned short* qkv   = w2t + 393216;                 // 8192*1536
  unsigned short* oproj = qkv + 12582912;               // 8192*512
  unsigned short* y     = oproj + 4194304;              // 8192*512
  float*          bqkv  = (float*)(y + 4194304);        // 1536 f32
  unsigned short* att   = xb;
  unsigned short* h     = qkv;
  unsigned short* f     = oproj;

  dim3 tb(32, 8);
  k_cvt<<<2048, 256, 0, stream>>>(x, xb, 8192 * 512 / 8);
  k_tpose<<<dim3(16, 16), tb, 0, stream>>>(Wq, wqkvt, 512, 512);
  k_tpose<<<dim3(16, 16), tb, 0, stream>>>(Wk, wqkvt + 512L * 512, 512, 512);
  k_tpose<<<dim3(16, 16), tb, 0, stream>>>(Wv, wqkvt + 1024L * 512, 512, 512);
  k_tpose<<<dim3(16, 16), tb, 0, stream>>>(Wo, wot, 512, 512);
  k_tpose<<<dim3(24, 16), tb, 0, stream>>>(W1, w1t, 512, 768);
  k_tpose<<<dim3(16, 24), tb, 0, stream>>>(W2, w2t, 768, 512);
  k_packb<<<6, 256, 0, stream>>>(bq, bk, bv, bqkv);

  // G1: qkv = x @ [Wq|Wk|Wv] + b
  k_gemm<0><<<dim3(12, 64), 256, 0, stream>>>(xb, wqkvt, bqkv, qkv, 8192, 1536, 512);
  // attention (pre-Wo output)
  k_attn<<<2048, 256, 0, stream>>>(qkv, adj, inx, att);
  // G2: oproj = relu(att @ Wo + bo)
  k_gemm<1><<<dim3(4, 64), 256, 0, stream>>>(att, wot, bo, oproj, 8192, 512, 512);
  // y = LN(x + oproj)
  k_ln1<<<2048, 256, 0, stream>>>(x, oproj, g1, be1, y);
  // G3: h = relu(y @ W1 + bf1)
  k_gemm<1><<<dim3(6, 64), 256, 0, stream>>>(y, w1t, bf1, h, 8192, 768, 512);
  // G4: f = h @ W2 + bf2
  k_gemm<0><<<dim3(4, 64), 256, 0, stream>>>(h, w2t, bf2, f, 8192, 512, 768);
  // out = LN(y + f)
  k_ln2<<<2048, 256, 0, stream>>>(y, f, g2, be2, (float*)d_out);
}

// Round 2
// 180.877 us; speedup vs baseline: 1.0394x; 1.0394x over previous
//
#include <hip/hip_runtime.h>
#include <stdint.h>

typedef __attribute__((ext_vector_type(8))) short short8;
typedef __attribute__((ext_vector_type(4))) float f32x4;

static __device__ __forceinline__ unsigned short f2bf(float f) {
  unsigned int u = __float_as_uint(f);
  u += 0x7FFFu + ((u >> 16) & 1u);
  return (unsigned short)(u >> 16);
}
static __device__ __forceinline__ float bf2f(unsigned short h) {
  return __uint_as_float(((unsigned int)h) << 16);
}

#define GLD16(gp, lp) __builtin_amdgcn_global_load_lds( \
    (__attribute__((address_space(1))) void*)(gp), \
    (__attribute__((address_space(3))) void*)(lp), 16, 0, 0)

// ---------------- fp32 -> bf16 elementwise (8 per thread) ----------------
__global__ __launch_bounds__(256) void k_cvt(const float* __restrict__ in,
                                             unsigned short* __restrict__ out,
                                             int n8) {
  int i = blockIdx.x * 256 + threadIdx.x;
  if (i >= n8) return;
  const float4* p = (const float4*)in + (long)i * 2;
  float4 a = p[0], b = p[1];
  short8 v;
  v[0] = (short)f2bf(a.x); v[1] = (short)f2bf(a.y);
  v[2] = (short)f2bf(a.z); v[3] = (short)f2bf(a.w);
  v[4] = (short)f2bf(b.x); v[5] = (short)f2bf(b.y);
  v[6] = (short)f2bf(b.z); v[7] = (short)f2bf(b.w);
  *(short8*)(out + (long)i * 8) = v;
}

// ---------------- fp32 [R][C] -> bf16 [C][R] transpose -------------------
__global__ __launch_bounds__(256) void k_tpose(const float* __restrict__ in,
                                               unsigned short* __restrict__ out,
                                               int R, int C) {
  __shared__ float tile[32][33];
  int tx = threadIdx.x, ty = threadIdx.y;
  int c0 = blockIdx.x * 32, r0 = blockIdx.y * 32;
#pragma unroll
  for (int i = 0; i < 4; i++)
    tile[ty + i * 8][tx] = in[(long)(r0 + ty + i * 8) * C + c0 + tx];
  __syncthreads();
#pragma unroll
  for (int i = 0; i < 4; i++)
    out[(long)(c0 + ty + i * 8) * R + r0 + tx] = f2bf(tile[tx][ty + i * 8]);
}

// ---------------- pack bq|bk|bv into one [1536] buffer -------------------
__global__ void k_packb(const float* __restrict__ a, const float* __restrict__ b,
                        const float* __restrict__ c, float* __restrict__ o) {
  int i = blockIdx.x * 256 + threadIdx.x;
  if (i < 512) o[i] = a[i];
  else if (i < 1024) o[i] = b[i - 512];
  else if (i < 1536) o[i] = c[i - 1024];
}

// ---------------- bf16 MFMA GEMM: C[M,N] = A[M,K] @ Bt[N,K]^T + bias ------
// 128x128 tile, BK=32, 4 waves (2x2), each wave 4x4 fragments of 16x16x32.
// EPI: 0 = bias, 1 = bias + relu. Output bf16.
template <int EPI>
__global__ __launch_bounds__(256) void k_gemm(const unsigned short* __restrict__ A,
                                              const unsigned short* __restrict__ Bt,
                                              const float* __restrict__ bias,
                                              unsigned short* __restrict__ C,
                                              int M, int N, int K) {
  __shared__ unsigned short As[128 * 32];
  __shared__ unsigned short Bs[128 * 32];
  const int t = threadIdx.x;
  const int lane = t & 63;
  const int w = t >> 6;
  const int wr = w >> 1, wc = w & 1;
  const int m0 = blockIdx.y * 128;
  const int n0 = blockIdx.x * 128;

  f32x4 acc[4][4];
#pragma unroll
  for (int mi = 0; mi < 4; mi++)
#pragma unroll
    for (int ni = 0; ni < 4; ni++) {
      f32x4 z = {0.f, 0.f, 0.f, 0.f};
      acc[mi][ni] = z;
    }

  // staging: tile [128][32] bf16 = 512 x 16B chunks; each thread 2 chunks
  const int c0 = t;
  const int c1 = t + 256;
  const int arow0 = c0 >> 2, acol0 = (c0 & 3) * 8;
  const int arow1 = c1 >> 2, acol1 = (c1 & 3) * 8;

  for (int k0 = 0; k0 < K; k0 += 32) {
    GLD16(A + (long)(m0 + arow0) * K + k0 + acol0, As + (long)c0 * 8);
    GLD16(A + (long)(m0 + arow1) * K + k0 + acol1, As + (long)c1 * 8);
    GLD16(Bt + (long)(n0 + arow0) * K + k0 + acol0, Bs + (long)c0 * 8);
    GLD16(Bt + (long)(n0 + arow1) * K + k0 + acol1, Bs + (long)c1 * 8);
    __syncthreads();

    short8 af[4], bf[4];
#pragma unroll
    for (int mi = 0; mi < 4; mi++)
      af[mi] = *(const short8*)&As[(wr * 64 + mi * 16 + (lane & 15)) * 32 + (lane >> 4) * 8];
#pragma unroll
    for (int ni = 0; ni < 4; ni++)
      bf[ni] = *(const short8*)&Bs[(wc * 64 + ni * 16 + (lane & 15)) * 32 + (lane >> 4) * 8];
#pragma unroll
    for (int mi = 0; mi < 4; mi++)
#pragma unroll
      for (int ni = 0; ni < 4; ni++)
        acc[mi][ni] = __builtin_amdgcn_mfma_f32_16x16x32_bf16(af[mi], bf[ni], acc[mi][ni], 0, 0, 0);
    __syncthreads();
  }

  const int lr = (lane >> 4) * 4;
  const int lc = lane & 15;
#pragma unroll
  for (int mi = 0; mi < 4; mi++) {
#pragma unroll
    for (int ni = 0; ni < 4; ni++) {
      const int col = n0 + wc * 64 + ni * 16 + lc;
      const float bv = bias[col];
#pragma unroll
      for (int r = 0; r < 4; r++) {
        const int row = m0 + wr * 64 + mi * 16 + lr + r;
        float v = acc[mi][ni][r] + bv;
        if (EPI == 1) v = fmaxf(v, 0.f);
        C[(long)row * N + col] = f2bf(v);
      }
    }
  }
}

// ---------------- attention: BLOCK per row, 4 waves x 8 neighbors ----------
// qkv: [8192][1536] bf16 (q | k | v). att: [8192][512] bf16 (pre-Wo).
// Wave w handles neighbors kk = w*8..w*8+7; scores via LDS; softmax computed
// redundantly per-thread; PV partials reduced through LDS.
__global__ __launch_bounds__(256) void k_attn(const unsigned short* __restrict__ qkv,
                                              const float* __restrict__ adj,
                                              const int* __restrict__ inxs,
                                              unsigned short* __restrict__ att) {
  __shared__ float s_sc[32];
  __shared__ float s_part[4][512];
  const int t = threadIdx.x;
  const int lane = t & 63;
  const int w = t >> 6;
  const int row = blockIdx.x;  // 0..8191
  const int b = row >> 11;
  const int n = row & 2047;

  const unsigned short* qp = qkv + (long)row * 1536 + lane * 8;
  short8 qv = *(const short8*)qp;
  float qf[8];
#pragma unroll
  for (int j = 0; j < 8; j++) qf[j] = bf2f((unsigned short)qv[j]);

  const int* ix = inxs + (long)row * 32;
  const float* adjrow = adj + ((long)b * 2048 + n) * 2048;

  int nb[8];
#pragma unroll
  for (int u = 0; u < 8; u++) nb[u] = ix[w * 8 + u];

  // scores for this wave's 8 neighbors
#pragma unroll
  for (int u = 0; u < 8; u++) {
    const int idx = nb[u];
    const unsigned short* kp = qkv + ((long)(b * 2048 + idx)) * 1536 + 512 + lane * 8;
    short8 kv = *(const short8*)kp;
    float d = 0.f;
#pragma unroll
    for (int j = 0; j < 8; j++) d += qf[j] * bf2f((unsigned short)kv[j]);
#pragma unroll
    for (int m = 32; m >= 1; m >>= 1) d += __shfl_xor(d, m, 64);
    if (lane == 0) {
      const float a = adjrow[idx];
      s_sc[w * 8 + u] = d * 0.044194173824159216f + (a > 0.f ? 0.f : -1e22f);
    }
  }
  __syncthreads();

  // softmax stats, computed redundantly by every thread (32 LDS broadcasts)
  float sc[32];
#pragma unroll
  for (int kk = 0; kk < 32; kk++) sc[kk] = s_sc[kk];
  float mx = sc[0];
#pragma unroll
  for (int kk = 1; kk < 32; kk++) mx = fmaxf(mx, sc[kk]);
  float ssum = 0.f;
#pragma unroll
  for (int kk = 0; kk < 32; kk++) ssum += __expf(sc[kk] - mx);
  const float inv = 1.f / ssum;

  // PV over this wave's 8 neighbors
  float o[8] = {0, 0, 0, 0, 0, 0, 0, 0};
#pragma unroll
  for (int u = 0; u < 8; u++) {
    const int idx = nb[u];
    const unsigned short* vp = qkv + ((long)(b * 2048 + idx)) * 1536 + 1024 + lane * 8;
    short8 vv = *(const short8*)vp;
    const float p = __expf(sc[w * 8 + u] - mx) * inv;
#pragma unroll
    for (int j = 0; j < 8; j++) o[j] += p * bf2f((unsigned short)vv[j]);
  }

  // partial reduce across the 4 waves through LDS
  f32x4* pp = (f32x4*)&s_part[w][lane * 8];
  f32x4 p0 = {o[0], o[1], o[2], o[3]};
  f32x4 p1 = {o[4], o[5], o[6], o[7]};
  pp[0] = p0;
  pp[1] = p1;
  __syncthreads();

  const int d0 = t * 2;
  float r0 = s_part[0][d0] + s_part[1][d0] + s_part[2][d0] + s_part[3][d0];
  float r1 = s_part[0][d0 + 1] + s_part[1][d0 + 1] + s_part[2][d0 + 1] + s_part[3][d0 + 1];
  *(unsigned int*)(att + (long)row * 512 + d0) =
      ((unsigned int)f2bf(r1) << 16) | (unsigned int)f2bf(r0);
}

// ---------------- LN1: y = LN(x_f32 + o_bf16) * g + beta, out bf16 --------
__global__ __launch_bounds__(256) void k_ln1(const float* __restrict__ x,
                                             const unsigned short* __restrict__ o,
                                             const float* __restrict__ g,
                                             const float* __restrict__ beta,
                                             unsigned short* __restrict__ y) {
  const int lane = threadIdx.x & 63;
  const int w = threadIdx.x >> 6;
  const long row = (long)blockIdx.x * 4 + w;
  const float4* xp = (const float4*)(x + row * 512 + lane * 8);
  float4 x0 = xp[0], x1 = xp[1];
  short8 ov = *(const short8*)(o + row * 512 + lane * 8);
  float tv[8] = {x0.x, x0.y, x0.z, x0.w, x1.x, x1.y, x1.z, x1.w};
  float s = 0.f, s2 = 0.f;
#pragma unroll
  for (int j = 0; j < 8; j++) {
    tv[j] += bf2f((unsigned short)ov[j]);
    s += tv[j];
    s2 += tv[j] * tv[j];
  }
#pragma unroll
  for (int m = 32; m >= 1; m >>= 1) {
    s += __shfl_xor(s, m, 64);
    s2 += __shfl_xor(s2, m, 64);
  }
  const float mean = s * (1.f / 512.f);
  const float var = s2 * (1.f / 512.f) - mean * mean;
  const float r = rsqrtf(var + 1e-5f);
  const float4* gp = (const float4*)(g + lane * 8);
  const float4* bp = (const float4*)(beta + lane * 8);
  float4 g0 = gp[0], g1v = gp[1], b0 = bp[0], b1 = bp[1];
  float gg[8] = {g0.x, g0.y, g0.z, g0.w, g1v.x, g1v.y, g1v.z, g1v.w};
  float bb[8] = {b0.x, b0.y, b0.z, b0.w, b1.x, b1.y, b1.z, b1.w};
  short8 yv;
#pragma unroll
  for (int j = 0; j < 8; j++) yv[j] = (short)f2bf((tv[j] - mean) * r * gg[j] + bb[j]);
  *(short8*)(y + row * 512 + lane * 8) = yv;
}

// ---------------- LN2: out_f32 = LN(y_bf16 + f_bf16) * g + beta -----------
__global__ __launch_bounds__(256) void k_ln2(const unsigned short* __restrict__ y,
                                             const unsigned short* __restrict__ f,
                                             const float* __restrict__ g,
                                             const float* __restrict__ beta,
                                             float* __restrict__ out) {
  const int lane = threadIdx.x & 63;
  const int w = threadIdx.x >> 6;
  const long row = (long)blockIdx.x * 4 + w;
  short8 yv = *(const short8*)(y + row * 512 + lane * 8);
  short8 fv = *(const short8*)(f + row * 512 + lane * 8);
  float tv[8];
  float s = 0.f, s2 = 0.f;
#pragma unroll
  for (int j = 0; j < 8; j++) {
    tv[j] = bf2f((unsigned short)yv[j]) + bf2f((unsigned short)fv[j]);
    s += tv[j];
    s2 += tv[j] * tv[j];
  }
#pragma unroll
  for (int m = 32; m >= 1; m >>= 1) {
    s += __shfl_xor(s, m, 64);
    s2 += __shfl_xor(s2, m, 64);
  }
  const float mean = s * (1.f / 512.f);
  const float var = s2 * (1.f / 512.f) - mean * mean;
  const float r = rsqrtf(var + 1e-5f);
  const float4* gp = (const float4*)(g + lane * 8);
  const float4* bp = (const float4*)(beta + lane * 8);
  float4 g0 = gp[0], g1v = gp[1], b0 = bp[0], b1 = bp[1];
  float gg[8] = {g0.x, g0.y, g0.z, g0.w, g1v.x, g1v.y, g1v.z, g1v.w};
  float bb[8] = {b0.x, b0.y, b0.z, b0.w, b1.x, b1.y, b1.z, b1.w};
  float ovv[8];
#pragma unroll
  for (int j = 0; j < 8; j++) ovv[j] = (tv[j] - mean) * r * gg[j] + bb[j];
  float4* op = (float4*)(out + row * 512 + lane * 8);
  float4 o0 = {ovv[0], ovv[1], ovv[2], ovv[3]};
  float4 o1 = {ovv[4], ovv[5], ovv[6], ovv[7]};
  op[0] = o0;
  op[1] = o1;
}

extern "C" void kernel_launch(void* const* d_in, const int* in_sizes, int n_in,
                              void* d_out, int out_size, void* d_ws, size_t ws_size,
                              hipStream_t stream) {
  const float* x   = (const float*)d_in[0];
  const float* adj = (const float*)d_in[1];
  const int*   inx = (const int*)d_in[2];
  const float* Wq  = (const float*)d_in[3];
  const float* bq  = (const float*)d_in[4];
  const float* Wk  = (const float*)d_in[5];
  const float* bk  = (const float*)d_in[6];
  const float* Wv  = (const float*)d_in[7];
  const float* bv  = (const float*)d_in[8];
  const float* Wo  = (const float*)d_in[9];
  const float* bo  = (const float*)d_in[10];
  const float* g1  = (const float*)d_in[11];
  const float* be1 = (const float*)d_in[12];
  const float* W1  = (const float*)d_in[13];
  const float* bf1 = (const float*)d_in[14];
  const float* W2  = (const float*)d_in[15];
  const float* bf2 = (const float*)d_in[16];
  const float* g2  = (const float*)d_in[17];
  const float* be2 = (const float*)d_in[18];

  // workspace layout (bf16 elements unless noted); aliased reuse is
  // stream-ordered-safe: att<-xb (xb dead after G1), h<-qkv (dead after attn),
  // f<-oproj (dead after LN1). Total ~54 MB.
  unsigned short* xb    = (unsigned short*)d_ws;        // 8192*512
  unsigned short* wqkvt = xb + 4194304;                 // 1536*512 (B^T)
  unsigned short* wot   = wqkvt + 786432;               // 512*512
  unsigned short* w1t   = wot + 262144;                 // 768*512
  unsigned short* w2t   = w1t + 393216;                 // 512*768
  unsigned short* qkv   = w2t + 393216;                 // 8192*1536
  unsigned short* oproj = qkv + 12582912;               // 8192*512
  unsigned short* y     = oproj + 4194304;              // 8192*512
  float*          bqkv  = (float*)(y + 4194304);        // 1536 f32
  unsigned short* att   = xb;
  unsigned short* h     = qkv;
  unsigned short* f     = oproj;

  dim3 tb(32, 8);
  k_cvt<<<2048, 256, 0, stream>>>(x, xb, 8192 * 512 / 8);
  k_tpose<<<dim3(16, 16), tb, 0, stream>>>(Wq, wqkvt, 512, 512);
  k_tpose<<<dim3(16, 16), tb, 0, stream>>>(Wk, wqkvt + 512L * 512, 512, 512);
  k_tpose<<<dim3(16, 16), tb, 0, stream>>>(Wv, wqkvt + 1024L * 512, 512, 512);
  k_tpose<<<dim3(16, 16), tb, 0, stream>>>(Wo, wot, 512, 512);
  k_tpose<<<dim3(24, 16), tb, 0, stream>>>(W1, w1t, 512, 768);
  k_tpose<<<dim3(16, 24), tb, 0, stream>>>(W2, w2t, 768, 512);
  k_packb<<<6, 256, 0, stream>>>(bq, bk, bv, bqkv);

  // G1: qkv = x @ [Wq|Wk|Wv] + b
  k_gemm<0><<<dim3(12, 64), 256, 0, stream>>>(xb, wqkvt, bqkv, qkv, 8192, 1536, 512);
  // attention (pre-Wo output)
  k_attn<<<8192, 256, 0, stream>>>(qkv, adj, inx, att);
  // G2: oproj = relu(att @ Wo + bo)
  k_gemm<1><<<dim3(4, 64), 256, 0, stream>>>(att, wot, bo, oproj, 8192, 512, 512);
  // y = LN(x + oproj)
  k_ln1<<<2048, 256, 0, stream>>>(x, oproj, g1, be1, y);
  // G3: h = relu(y @ W1 + bf1)
  k_gemm<1><<<dim3(6, 64), 256, 0, stream>>>(y, w1t, bf1, h, 8192, 768, 512);
  // G4: f = h @ W2 + bf2
  k_gemm<0><<<dim3(4, 64), 256, 0, stream>>>(h, w2t, bf2, f, 8192, 512, 768);
  // out = LN(y + f)
  k_ln2<<<2048, 256, 0, stream>>>(y, f, g2, be2, (float*)d_out);
}

// Round 3
// 155.085 us; speedup vs baseline: 1.2123x; 1.1663x over previous
//
#include <hip/hip_runtime.h>
#include <stdint.h>

typedef __attribute__((ext_vector_type(8))) short short8;
typedef __attribute__((ext_vector_type(4))) float f32x4;
typedef __attribute__((ext_vector_type(2))) _Float16 h2;
typedef __attribute__((ext_vector_type(8))) _Float16 half8;

static __device__ __forceinline__ unsigned short f2bf(float f) {
  unsigned int u = __float_as_uint(f);
  u += 0x7FFFu + ((u >> 16) & 1u);
  return (unsigned short)(u >> 16);
}
static __device__ __forceinline__ float bf2f(unsigned short h) {
  return __uint_as_float(((unsigned int)h) << 16);
}
static __device__ __forceinline__ unsigned short f2h(float f) {
  _Float16 h = (_Float16)f;
  return __builtin_bit_cast(unsigned short, h);
}
static __device__ __forceinline__ float hdot2(unsigned int a, unsigned int b, float c) {
  return __builtin_amdgcn_fdot2(__builtin_bit_cast(h2, a), __builtin_bit_cast(h2, b), c, false);
}

#define GLD16(gp, lp) __builtin_amdgcn_global_load_lds( \
    (__attribute__((address_space(1))) void*)(gp), \
    (__attribute__((address_space(3))) void*)(lp), 16, 0, 0)

// ---------------- fp32 -> f16/bf16 elementwise (8 per thread) -------------
template <int F16>
__global__ __launch_bounds__(256) void k_cvt(const float* __restrict__ in,
                                             unsigned short* __restrict__ out,
                                             int n8) {
  int i = blockIdx.x * 256 + threadIdx.x;
  if (i >= n8) return;
  const float4* p = (const float4*)in + (long)i * 2;
  float4 a = p[0], b = p[1];
  short8 v;
  if (F16) {
    v[0] = (short)f2h(a.x); v[1] = (short)f2h(a.y);
    v[2] = (short)f2h(a.z); v[3] = (short)f2h(a.w);
    v[4] = (short)f2h(b.x); v[5] = (short)f2h(b.y);
    v[6] = (short)f2h(b.z); v[7] = (short)f2h(b.w);
  } else {
    v[0] = (short)f2bf(a.x); v[1] = (short)f2bf(a.y);
    v[2] = (short)f2bf(a.z); v[3] = (short)f2bf(a.w);
    v[4] = (short)f2bf(b.x); v[5] = (short)f2bf(b.y);
    v[6] = (short)f2bf(b.z); v[7] = (short)f2bf(b.w);
  }
  *(short8*)(out + (long)i * 8) = v;
}

// ---------------- fp32 [R][C] -> f16/bf16 [C][R] transpose ----------------
template <int F16>
__global__ __launch_bounds__(256) void k_tpose(const float* __restrict__ in,
                                               unsigned short* __restrict__ out,
                                               int R, int C) {
  __shared__ float tile[32][33];
  int tx = threadIdx.x, ty = threadIdx.y;
  int c0 = blockIdx.x * 32, r0 = blockIdx.y * 32;
#pragma unroll
  for (int i = 0; i < 4; i++)
    tile[ty + i * 8][tx] = in[(long)(r0 + ty + i * 8) * C + c0 + tx];
  __syncthreads();
#pragma unroll
  for (int i = 0; i < 4; i++) {
    float v = tile[tx][ty + i * 8];
    out[(long)(c0 + ty + i * 8) * R + r0 + tx] = F16 ? f2h(v) : f2bf(v);
  }
}

// ---------------- pack bq|bk|bv into one [1536] buffer -------------------
__global__ void k_packb(const float* __restrict__ a, const float* __restrict__ b,
                        const float* __restrict__ c, float* __restrict__ o) {
  int i = blockIdx.x * 256 + threadIdx.x;
  if (i < 512) o[i] = a[i];
  else if (i < 1024) o[i] = b[i - 512];
  else if (i < 1536) o[i] = c[i - 1024];
}

// ---------------- 16-bit MFMA GEMM: C[M,N] = A[M,K] @ Bt[N,K]^T + bias ----
// 128x128 tile, BK=32, 4 waves (2x2), each wave 4x4 fragments of 16x16x32.
// EPI: 0 = bias, 1 = bias + relu. F16: fp16 in/out, else bf16 in/out.
template <int EPI, int F16>
__global__ __launch_bounds__(256) void k_gemm(const unsigned short* __restrict__ A,
                                              const unsigned short* __restrict__ Bt,
                                              const float* __restrict__ bias,
                                              unsigned short* __restrict__ C,
                                              int M, int N, int K) {
  __shared__ unsigned short As[128 * 32];
  __shared__ unsigned short Bs[128 * 32];
  const int t = threadIdx.x;
  const int lane = t & 63;
  const int w = t >> 6;
  const int wr = w >> 1, wc = w & 1;
  const int m0 = blockIdx.y * 128;
  const int n0 = blockIdx.x * 128;

  f32x4 acc[4][4];
#pragma unroll
  for (int mi = 0; mi < 4; mi++)
#pragma unroll
    for (int ni = 0; ni < 4; ni++) {
      f32x4 z = {0.f, 0.f, 0.f, 0.f};
      acc[mi][ni] = z;
    }

  const int c0 = t;
  const int c1 = t + 256;
  const int arow0 = c0 >> 2, acol0 = (c0 & 3) * 8;
  const int arow1 = c1 >> 2, acol1 = (c1 & 3) * 8;

  for (int k0 = 0; k0 < K; k0 += 32) {
    GLD16(A + (long)(m0 + arow0) * K + k0 + acol0, As + (long)c0 * 8);
    GLD16(A + (long)(m0 + arow1) * K + k0 + acol1, As + (long)c1 * 8);
    GLD16(Bt + (long)(n0 + arow0) * K + k0 + acol0, Bs + (long)c0 * 8);
    GLD16(Bt + (long)(n0 + arow1) * K + k0 + acol1, Bs + (long)c1 * 8);
    __syncthreads();

    short8 af[4], bf[4];
#pragma unroll
    for (int mi = 0; mi < 4; mi++)
      af[mi] = *(const short8*)&As[(wr * 64 + mi * 16 + (lane & 15)) * 32 + (lane >> 4) * 8];
#pragma unroll
    for (int ni = 0; ni < 4; ni++)
      bf[ni] = *(const short8*)&Bs[(wc * 64 + ni * 16 + (lane & 15)) * 32 + (lane >> 4) * 8];
#pragma unroll
    for (int mi = 0; mi < 4; mi++)
#pragma unroll
      for (int ni = 0; ni < 4; ni++) {
        if (F16)
          acc[mi][ni] = __builtin_amdgcn_mfma_f32_16x16x32_f16(
              __builtin_bit_cast(half8, af[mi]), __builtin_bit_cast(half8, bf[ni]),
              acc[mi][ni], 0, 0, 0);
        else
          acc[mi][ni] = __builtin_amdgcn_mfma_f32_16x16x32_bf16(af[mi], bf[ni], acc[mi][ni], 0, 0, 0);
      }
    __syncthreads();
  }

  const int lr = (lane >> 4) * 4;
  const int lc = lane & 15;
#pragma unroll
  for (int mi = 0; mi < 4; mi++) {
#pragma unroll
    for (int ni = 0; ni < 4; ni++) {
      const int col = n0 + wc * 64 + ni * 16 + lc;
      const float bv = bias[col];
#pragma unroll
      for (int r = 0; r < 4; r++) {
        const int row = m0 + wr * 64 + mi * 16 + lr + r;
        float v = acc[mi][ni][r] + bv;
        if (EPI == 1) v = fmaxf(v, 0.f);
        C[(long)row * N + col] = F16 ? f2h(v) : f2bf(v);
      }
    }
  }
}

// ---------------- attention: BLOCK per row, fp16 qkv, v_dot2 --------------
// qkv: [8192][1536] f16 (q | k | v). att: [8192][512] bf16 (pre-Wo).
// Scores: 16 lanes per neighbor (4 in flight per wave), 2 rounds -> 8/wave.
// PV: neighbor pairs packed via v_perm, fdot2 into f32 accumulators.
__global__ __launch_bounds__(256) void k_attn(const unsigned short* __restrict__ qkv,
                                              const float* __restrict__ adj,
                                              const int* __restrict__ inxs,
                                              unsigned short* __restrict__ att) {
  __shared__ float s_sc[32];
  __shared__ float s_part[4][512];
  const int t = threadIdx.x;
  const int lane = t & 63;
  const int w = t >> 6;
  const int g = lane >> 4;   // group 0..3
  const int li = lane & 15;  // lane in group
  const int row = blockIdx.x;
  const int b = row >> 11;
  const long base = (long)b * 2048;

  const int* ix = inxs + (long)row * 32;
  const float* adjrow = adj + (long)row * 2048;

  // q chunks for the dot: lane-in-group li covers chunks {li, li+16, li+32, li+48}
  const uint4* qp = (const uint4*)(qkv + (long)row * 1536);
  uint4 qc[4];
#pragma unroll
  for (int c = 0; c < 4; c++) qc[c] = qp[li + c * 16];

  // scores: 2 rounds x 4 concurrent neighbors (one per 16-lane group)
#pragma unroll
  for (int r = 0; r < 2; r++) {
    const int nb = ix[w * 8 + r * 4 + g];
    const uint4* kp = (const uint4*)(qkv + (base + nb) * 1536 + 512);
    float d = 0.f;
#pragma unroll
    for (int c = 0; c < 4; c++) {
      uint4 kc = kp[li + c * 16];
      d = hdot2(kc.x, qc[c].x, d);
      d = hdot2(kc.y, qc[c].y, d);
      d = hdot2(kc.z, qc[c].z, d);
      d = hdot2(kc.w, qc[c].w, d);
    }
#pragma unroll
    for (int m = 1; m <= 8; m <<= 1) d += __shfl_xor(d, m, 64);
    if (li == 0) {
      const float a = adjrow[nb];
      s_sc[w * 8 + r * 4 + g] = d * 0.044194173824159216f + (a > 0.f ? 0.f : -1e22f);
    }
  }
  __syncthreads();

  // softmax stats (redundant per thread; LDS reads broadcast)
  float mx = s_sc[0];
#pragma unroll
  for (int kk = 1; kk < 32; kk++) mx = fmaxf(mx, s_sc[kk]);
  float ssum = 0.f;
#pragma unroll
  for (int kk = 0; kk < 32; kk++) ssum += __expf(s_sc[kk] - mx);
  const float inv = 1.f / ssum;

  // PV: this wave's 8 neighbors as 4 pairs; each lane covers feats lane*8..+8
  float o[8] = {0, 0, 0, 0, 0, 0, 0, 0};
#pragma unroll
  for (int p = 0; p < 4; p++) {
    const int u0 = ix[w * 8 + 2 * p];
    const int u1 = ix[w * 8 + 2 * p + 1];
    const uint4* v0p = (const uint4*)(qkv + (base + u0) * 1536 + 1024);
    const uint4* v1p = (const uint4*)(qkv + (base + u1) * 1536 + 1024);
    uint4 v0c = v0p[lane];
    uint4 v1c = v1p[lane];
    const float pe0 = __expf(s_sc[w * 8 + 2 * p] - mx);
    const float pe1 = __expf(s_sc[w * 8 + 2 * p + 1] - mx);
    const unsigned int pp =
        __builtin_bit_cast(unsigned int, __builtin_amdgcn_cvt_pkrtz(pe0, pe1));
    const unsigned int vw0[4] = {v0c.x, v0c.y, v0c.z, v0c.w};
    const unsigned int vw1[4] = {v1c.x, v1c.y, v1c.z, v1c.w};
#pragma unroll
    for (int q = 0; q < 4; q++) {
      const unsigned int even = __builtin_amdgcn_perm(vw1[q], vw0[q], 0x05040100u);
      const unsigned int odd  = __builtin_amdgcn_perm(vw1[q], vw0[q], 0x07060302u);
      o[2 * q]     = hdot2(even, pp, o[2 * q]);
      o[2 * q + 1] = hdot2(odd,  pp, o[2 * q + 1]);
    }
  }
#pragma unroll
  for (int j = 0; j < 8; j++) o[j] *= inv;

  // partial reduce across the 4 waves through LDS
  f32x4* ppart = (f32x4*)&s_part[w][lane * 8];
  f32x4 p0 = {o[0], o[1], o[2], o[3]};
  f32x4 p1 = {o[4], o[5], o[6], o[7]};
  ppart[0] = p0;
  ppart[1] = p1;
  __syncthreads();

  const int d0 = t * 2;
  float r0 = s_part[0][d0] + s_part[1][d0] + s_part[2][d0] + s_part[3][d0];
  float r1 = s_part[0][d0 + 1] + s_part[1][d0 + 1] + s_part[2][d0 + 1] + s_part[3][d0 + 1];
  *(unsigned int*)(att + (long)row * 512 + d0) =
      ((unsigned int)f2bf(r1) << 16) | (unsigned int)f2bf(r0);
}

// ---------------- LN1: y = LN(x_f32 + o_bf16) * g + beta, out bf16 --------
__global__ __launch_bounds__(256) void k_ln1(const float* __restrict__ x,
                                             const unsigned short* __restrict__ o,
                                             const float* __restrict__ g,
                                             const float* __restrict__ beta,
                                             unsigned short* __restrict__ y) {
  const int lane = threadIdx.x & 63;
  const int w = threadIdx.x >> 6;
  const long row = (long)blockIdx.x * 4 + w;
  const float4* xp = (const float4*)(x + row * 512 + lane * 8);
  float4 x0 = xp[0], x1 = xp[1];
  short8 ov = *(const short8*)(o + row * 512 + lane * 8);
  float tv[8] = {x0.x, x0.y, x0.z, x0.w, x1.x, x1.y, x1.z, x1.w};
  float s = 0.f, s2 = 0.f;
#pragma unroll
  for (int j = 0; j < 8; j++) {
    tv[j] += bf2f((unsigned short)ov[j]);
    s += tv[j];
    s2 += tv[j] * tv[j];
  }
#pragma unroll
  for (int m = 32; m >= 1; m >>= 1) {
    s += __shfl_xor(s, m, 64);
    s2 += __shfl_xor(s2, m, 64);
  }
  const float mean = s * (1.f / 512.f);
  const float var = s2 * (1.f / 512.f) - mean * mean;
  const float r = rsqrtf(var + 1e-5f);
  const float4* gp = (const float4*)(g + lane * 8);
  const float4* bp = (const float4*)(beta + lane * 8);
  float4 g0 = gp[0], g1v = gp[1], b0 = bp[0], b1 = bp[1];
  float gg[8] = {g0.x, g0.y, g0.z, g0.w, g1v.x, g1v.y, g1v.z, g1v.w};
  float bb[8] = {b0.x, b0.y, b0.z, b0.w, b1.x, b1.y, b1.z, b1.w};
  short8 yv;
#pragma unroll
  for (int j = 0; j < 8; j++) yv[j] = (short)f2bf((tv[j] - mean) * r * gg[j] + bb[j]);
  *(short8*)(y + row * 512 + lane * 8) = yv;
}

// ---------------- LN2: out_f32 = LN(y_bf16 + f_bf16) * g + beta -----------
__global__ __launch_bounds__(256) void k_ln2(const unsigned short* __restrict__ y,
                                             const unsigned short* __restrict__ f,
                                             const float* __restrict__ g,
                                             const float* __restrict__ beta,
                                             float* __restrict__ out) {
  const int lane = threadIdx.x & 63;
  const int w = threadIdx.x >> 6;
  const long row = (long)blockIdx.x * 4 + w;
  short8 yv = *(const short8*)(y + row * 512 + lane * 8);
  short8 fv = *(const short8*)(f + row * 512 + lane * 8);
  float tv[8];
  float s = 0.f, s2 = 0.f;
#pragma unroll
  for (int j = 0; j < 8; j++) {
    tv[j] = bf2f((unsigned short)yv[j]) + bf2f((unsigned short)fv[j]);
    s += tv[j];
    s2 += tv[j] * tv[j];
  }
#pragma unroll
  for (int m = 32; m >= 1; m >>= 1) {
    s += __shfl_xor(s, m, 64);
    s2 += __shfl_xor(s2, m, 64);
  }
  const float mean = s * (1.f / 512.f);
  const float var = s2 * (1.f / 512.f) - mean * mean;
  const float r = rsqrtf(var + 1e-5f);
  const float4* gp = (const float4*)(g + lane * 8);
  const float4* bp = (const float4*)(beta + lane * 8);
  float4 g0 = gp[0], g1v = gp[1], b0 = bp[0], b1 = bp[1];
  float gg[8] = {g0.x, g0.y, g0.z, g0.w, g1v.x, g1v.y, g1v.z, g1v.w};
  float bb[8] = {b0.x, b0.y, b0.z, b0.w, b1.x, b1.y, b1.z, b1.w};
  float ovv[8];
#pragma unroll
  for (int j = 0; j < 8; j++) ovv[j] = (tv[j] - mean) * r * gg[j] + bb[j];
  float4* op = (float4*)(out + row * 512 + lane * 8);
  float4 o0 = {ovv[0], ovv[1], ovv[2], ovv[3]};
  float4 o1 = {ovv[4], ovv[5], ovv[6], ovv[7]};
  op[0] = o0;
  op[1] = o1;
}

extern "C" void kernel_launch(void* const* d_in, const int* in_sizes, int n_in,
                              void* d_out, int out_size, void* d_ws, size_t ws_size,
                              hipStream_t stream) {
  const float* x   = (const float*)d_in[0];
  const float* adj = (const float*)d_in[1];
  const int*   inx = (const int*)d_in[2];
  const float* Wq  = (const float*)d_in[3];
  const float* bq  = (const float*)d_in[4];
  const float* Wk  = (const float*)d_in[5];
  const float* bk  = (const float*)d_in[6];
  const float* Wv  = (const float*)d_in[7];
  const float* bv  = (const float*)d_in[8];
  const float* Wo  = (const float*)d_in[9];
  const float* bo  = (const float*)d_in[10];
  const float* g1  = (const float*)d_in[11];
  const float* be1 = (const float*)d_in[12];
  const float* W1  = (const float*)d_in[13];
  const float* bf1 = (const float*)d_in[14];
  const float* W2  = (const float*)d_in[15];
  const float* bf2 = (const float*)d_in[16];
  const float* g2  = (const float*)d_in[17];
  const float* be2 = (const float*)d_in[18];

  // workspace layout; aliased reuse is stream-ordered-safe:
  // att<-xb (xb dead after G1), h<-qkv (dead after attn), f<-oproj (dead after LN1)
  unsigned short* xb    = (unsigned short*)d_ws;        // 8192*512 (f16)
  unsigned short* wqkvt = xb + 4194304;                 // 1536*512 (f16, B^T)
  unsigned short* wot   = wqkvt + 786432;               // 512*512 (bf16)
  unsigned short* w1t   = wot + 262144;                 // 768*512 (bf16)
  unsigned short* w2t   = w1t + 393216;                 // 512*768 (bf16)
  unsigned short* qkv   = w2t + 393216;                 // 8192*1536 (f16)
  unsigned short* oproj = qkv + 12582912;               // 8192*512 (bf16)
  unsigned short* y     = oproj + 4194304;              // 8192*512 (bf16)
  float*          bqkv  = (float*)(y + 4194304);        // 1536 f32
  unsigned short* att   = xb;                           // bf16
  unsigned short* h     = qkv;                          // bf16
  unsigned short* f     = oproj;                        // bf16

  dim3 tb(32, 8);
  k_cvt<1><<<2048, 256, 0, stream>>>(x, xb, 8192 * 512 / 8);
  k_tpose<1><<<dim3(16, 16), tb, 0, stream>>>(Wq, wqkvt, 512, 512);
  k_tpose<1><<<dim3(16, 16), tb, 0, stream>>>(Wk, wqkvt + 512L * 512, 512, 512);
  k_tpose<1><<<dim3(16, 16), tb, 0, stream>>>(Wv, wqkvt + 1024L * 512, 512, 512);
  k_tpose<0><<<dim3(16, 16), tb, 0, stream>>>(Wo, wot, 512, 512);
  k_tpose<0><<<dim3(24, 16), tb, 0, stream>>>(W1, w1t, 512, 768);
  k_tpose<0><<<dim3(16, 24), tb, 0, stream>>>(W2, w2t, 768, 512);
  k_packb<<<6, 256, 0, stream>>>(bq, bk, bv, bqkv);

  // G1: qkv = x @ [Wq|Wk|Wv] + b   (fp16)
  k_gemm<0, 1><<<dim3(12, 64), 256, 0, stream>>>(xb, wqkvt, bqkv, qkv, 8192, 1536, 512);
  // attention (pre-Wo output, bf16)
  k_attn<<<8192, 256, 0, stream>>>(qkv, adj, inx, att);
  // G2: oproj = relu(att @ Wo + bo)
  k_gemm<1, 0><<<dim3(4, 64), 256, 0, stream>>>(att, wot, bo, oproj, 8192, 512, 512);
  // y = LN(x + oproj)
  k_ln1<<<2048, 256, 0, stream>>>(x, oproj, g1, be1, y);
  // G3: h = relu(y @ W1 + bf1)
  k_gemm<1, 0><<<dim3(6, 64), 256, 0, stream>>>(y, w1t, bf1, h, 8192, 768, 512);
  // G4: f = h @ W2 + bf2
  k_gemm<0, 0><<<dim3(4, 64), 256, 0, stream>>>(h, w2t, bf2, f, 8192, 512, 768);
  // out = LN(y + f)
  k_ln2<<<2048, 256, 0, stream>>>(y, f, g2, be2, (float*)d_out);
}

// Round 4
// 149.212 us; speedup vs baseline: 1.2600x; 1.0394x over previous
//
#include <hip/hip_runtime.h>
#include <stdint.h>

typedef __attribute__((ext_vector_type(8))) short short8;
typedef __attribute__((ext_vector_type(4))) float f32x4;
typedef __attribute__((ext_vector_type(2))) _Float16 h2;
typedef __attribute__((ext_vector_type(8))) _Float16 half8;

static __device__ __forceinline__ unsigned short f2bf(float f) {
  unsigned int u = __float_as_uint(f);
  u += 0x7FFFu + ((u >> 16) & 1u);
  return (unsigned short)(u >> 16);
}
static __device__ __forceinline__ float bf2f(unsigned short h) {
  return __uint_as_float(((unsigned int)h) << 16);
}
static __device__ __forceinline__ unsigned short f2h(float f) {
  _Float16 h = (_Float16)f;
  return __builtin_bit_cast(unsigned short, h);
}
static __device__ __forceinline__ float hdot2(unsigned int a, unsigned int b, float c) {
  return __builtin_amdgcn_fdot2(__builtin_bit_cast(h2, a), __builtin_bit_cast(h2, b), c, false);
}

#define GLD16(gp, lp) __builtin_amdgcn_global_load_lds( \
    (__attribute__((address_space(1))) void*)(gp), \
    (__attribute__((address_space(3))) void*)(lp), 16, 0, 0)

// ---------------- fp32 -> f16/bf16 elementwise (8 per thread) -------------
template <int F16>
__global__ __launch_bounds__(256) void k_cvt(const float* __restrict__ in,
                                             unsigned short* __restrict__ out,
                                             int n8) {
  int i = blockIdx.x * 256 + threadIdx.x;
  if (i >= n8) return;
  const float4* p = (const float4*)in + (long)i * 2;
  float4 a = p[0], b = p[1];
  short8 v;
  if (F16) {
    v[0] = (short)f2h(a.x); v[1] = (short)f2h(a.y);
    v[2] = (short)f2h(a.z); v[3] = (short)f2h(a.w);
    v[4] = (short)f2h(b.x); v[5] = (short)f2h(b.y);
    v[6] = (short)f2h(b.z); v[7] = (short)f2h(b.w);
  } else {
    v[0] = (short)f2bf(a.x); v[1] = (short)f2bf(a.y);
    v[2] = (short)f2bf(a.z); v[3] = (short)f2bf(a.w);
    v[4] = (short)f2bf(b.x); v[5] = (short)f2bf(b.y);
    v[6] = (short)f2bf(b.z); v[7] = (short)f2bf(b.w);
  }
  *(short8*)(out + (long)i * 8) = v;
}

// ---------------- fp32 [R][C] -> f16/bf16 [C][R] transpose ----------------
template <int F16>
__global__ __launch_bounds__(256) void k_tpose(const float* __restrict__ in,
                                               unsigned short* __restrict__ out,
                                               int R, int C) {
  __shared__ float tile[32][33];
  int tx = threadIdx.x, ty = threadIdx.y;
  int c0 = blockIdx.x * 32, r0 = blockIdx.y * 32;
#pragma unroll
  for (int i = 0; i < 4; i++)
    tile[ty + i * 8][tx] = in[(long)(r0 + ty + i * 8) * C + c0 + tx];
  __syncthreads();
#pragma unroll
  for (int i = 0; i < 4; i++) {
    float v = tile[tx][ty + i * 8];
    out[(long)(c0 + ty + i * 8) * R + r0 + tx] = F16 ? f2h(v) : f2bf(v);
  }
}

// ---------------- pack bq|bk|bv into one [1536] buffer -------------------
__global__ void k_packb(const float* __restrict__ a, const float* __restrict__ b,
                        const float* __restrict__ c, float* __restrict__ o) {
  int i = blockIdx.x * 256 + threadIdx.x;
  if (i < 512) o[i] = a[i];
  else if (i < 1024) o[i] = b[i - 512];
  else if (i < 1536) o[i] = c[i - 1024];
}

// ---------------- 16-bit MFMA GEMM: C[M,N] = A[M,K] @ Bt[N,K]^T + bias ----
// 128x128 tile, BK=32, 4 waves (2x2), each wave 4x4 fragments of 16x16x32.
// EPI: 0 = bias, 1 = bias + relu. F16: fp16 in/out, else bf16 in/out.
template <int EPI, int F16>
__global__ __launch_bounds__(256) void k_gemm(const unsigned short* __restrict__ A,
                                              const unsigned short* __restrict__ Bt,
                                              const float* __restrict__ bias,
                                              unsigned short* __restrict__ C,
                                              int M, int N, int K) {
  __shared__ unsigned short As[128 * 32];
  __shared__ unsigned short Bs[128 * 32];
  const int t = threadIdx.x;
  const int lane = t & 63;
  const int w = t >> 6;
  const int wr = w >> 1, wc = w & 1;
  const int m0 = blockIdx.y * 128;
  const int n0 = blockIdx.x * 128;

  f32x4 acc[4][4];
#pragma unroll
  for (int mi = 0; mi < 4; mi++)
#pragma unroll
    for (int ni = 0; ni < 4; ni++) {
      f32x4 z = {0.f, 0.f, 0.f, 0.f};
      acc[mi][ni] = z;
    }

  const int c0 = t;
  const int c1 = t + 256;
  const int arow0 = c0 >> 2, acol0 = (c0 & 3) * 8;
  const int arow1 = c1 >> 2, acol1 = (c1 & 3) * 8;

  for (int k0 = 0; k0 < K; k0 += 32) {
    GLD16(A + (long)(m0 + arow0) * K + k0 + acol0, As + (long)c0 * 8);
    GLD16(A + (long)(m0 + arow1) * K + k0 + acol1, As + (long)c1 * 8);
    GLD16(Bt + (long)(n0 + arow0) * K + k0 + acol0, Bs + (long)c0 * 8);
    GLD16(Bt + (long)(n0 + arow1) * K + k0 + acol1, Bs + (long)c1 * 8);
    __syncthreads();

    short8 af[4], bf[4];
#pragma unroll
    for (int mi = 0; mi < 4; mi++)
      af[mi] = *(const short8*)&As[(wr * 64 + mi * 16 + (lane & 15)) * 32 + (lane >> 4) * 8];
#pragma unroll
    for (int ni = 0; ni < 4; ni++)
      bf[ni] = *(const short8*)&Bs[(wc * 64 + ni * 16 + (lane & 15)) * 32 + (lane >> 4) * 8];
#pragma unroll
    for (int mi = 0; mi < 4; mi++)
#pragma unroll
      for (int ni = 0; ni < 4; ni++) {
        if (F16)
          acc[mi][ni] = __builtin_amdgcn_mfma_f32_16x16x32_f16(
              __builtin_bit_cast(half8, af[mi]), __builtin_bit_cast(half8, bf[ni]),
              acc[mi][ni], 0, 0, 0);
        else
          acc[mi][ni] = __builtin_amdgcn_mfma_f32_16x16x32_bf16(af[mi], bf[ni], acc[mi][ni], 0, 0, 0);
      }
    __syncthreads();
  }

  const int lr = (lane >> 4) * 4;
  const int lc = lane & 15;
#pragma unroll
  for (int mi = 0; mi < 4; mi++) {
#pragma unroll
    for (int ni = 0; ni < 4; ni++) {
      const int col = n0 + wc * 64 + ni * 16 + lc;
      const float bv = bias[col];
#pragma unroll
      for (int r = 0; r < 4; r++) {
        const int row = m0 + wr * 64 + mi * 16 + lr + r;
        float v = acc[mi][ni][r] + bv;
        if (EPI == 1) v = fmaxf(v, 0.f);
        C[(long)row * N + col] = F16 ? f2h(v) : f2bf(v);
      }
    }
  }
}

// ---------------- attention: BLOCK per row, fp16 qkv, v_dot2 --------------
// XCD-batch swizzle: hardware round-robins blockIdx across the 8 XCDs, so
// route batch b to XCDs {2b,2b+1}. Each XCD's L2 (4 MB) then only needs its
// batch's k+v (4 MB) -> gathers hit local L2 instead of L3.
// Softmax: wave-parallel (lane kk owns score kk), PV weights via shfl.
__global__ __launch_bounds__(256) void k_attn(const unsigned short* __restrict__ qkv,
                                              const float* __restrict__ adj,
                                              const int* __restrict__ inxs,
                                              unsigned short* __restrict__ att) {
  __shared__ float s_sc[32];
  __shared__ float s_part[4][512];
  const int t = threadIdx.x;
  const int lane = t & 63;
  const int w = t >> 6;
  const int g = lane >> 4;   // group 0..3
  const int li = lane & 15;  // lane in group
  const int bid = blockIdx.x;
  const int xcd = bid & 7;
  const int b = xcd >> 1;                       // batch 0..3 on XCDs {2b,2b+1}
  const int sub = ((bid >> 3) << 1) | (xcd & 1);  // 0..2047, bijective
  const int row = (b << 11) | sub;
  const long base = (long)b * 2048;

  const int* ix = inxs + (long)row * 32;
  const float* adjrow = adj + (long)row * 2048;

  // q chunks: lane-in-group li covers uint4 chunks {li, li+16, li+32, li+48}
  const uint4* qp = (const uint4*)(qkv + (long)row * 1536);
  uint4 qc[4];
#pragma unroll
  for (int c = 0; c < 4; c++) qc[c] = qp[li + c * 16];

  // scores: 2 rounds x 4 concurrent neighbors (one per 16-lane group)
#pragma unroll
  for (int r = 0; r < 2; r++) {
    const int nb = ix[w * 8 + r * 4 + g];
    const uint4* kp = (const uint4*)(qkv + (base + nb) * 1536 + 512);
    float d = 0.f;
#pragma unroll
    for (int c = 0; c < 4; c++) {
      uint4 kc = kp[li + c * 16];
      d = hdot2(kc.x, qc[c].x, d);
      d = hdot2(kc.y, qc[c].y, d);
      d = hdot2(kc.z, qc[c].z, d);
      d = hdot2(kc.w, qc[c].w, d);
    }
#pragma unroll
    for (int m = 1; m <= 8; m <<= 1) d += __shfl_xor(d, m, 64);
    if (li == 0) {
      const float a = adjrow[nb];
      s_sc[w * 8 + r * 4 + g] = d * 0.044194173824159216f + (a > 0.f ? 0.f : -1e22f);
    }
  }
  __syncthreads();

  // wave-parallel softmax: lane kk (and kk+32) owns score kk
  const int kk = lane & 31;
  float s = s_sc[kk];
  float mx = s;
#pragma unroll
  for (int d = 1; d <= 16; d <<= 1) mx = fmaxf(mx, __shfl_xor(mx, d, 64));
  float e = __expf(s - mx);
  float ts = e;
#pragma unroll
  for (int d = 1; d <= 16; d <<= 1) ts += __shfl_xor(ts, d, 64);
  const float inv = 1.f / ts;

  // PV: this wave's 8 neighbors as 4 pairs; each lane covers feats lane*8..+8
  float o[8] = {0, 0, 0, 0, 0, 0, 0, 0};
#pragma unroll
  for (int p = 0; p < 4; p++) {
    const int u0 = ix[w * 8 + 2 * p];
    const int u1 = ix[w * 8 + 2 * p + 1];
    const uint4* v0p = (const uint4*)(qkv + (base + u0) * 1536 + 1024);
    const uint4* v1p = (const uint4*)(qkv + (base + u1) * 1536 + 1024);
    uint4 v0c = v0p[lane];
    uint4 v1c = v1p[lane];
    const float pe0 = __shfl(e, w * 8 + 2 * p, 64);
    const float pe1 = __shfl(e, w * 8 + 2 * p + 1, 64);
    const unsigned int pp =
        __builtin_bit_cast(unsigned int, __builtin_amdgcn_cvt_pkrtz(pe0, pe1));
    const unsigned int vw0[4] = {v0c.x, v0c.y, v0c.z, v0c.w};
    const unsigned int vw1[4] = {v1c.x, v1c.y, v1c.z, v1c.w};
#pragma unroll
    for (int q = 0; q < 4; q++) {
      const unsigned int even = __builtin_amdgcn_perm(vw1[q], vw0[q], 0x05040100u);
      const unsigned int odd  = __builtin_amdgcn_perm(vw1[q], vw0[q], 0x07060302u);
      o[2 * q]     = hdot2(even, pp, o[2 * q]);
      o[2 * q + 1] = hdot2(odd,  pp, o[2 * q + 1]);
    }
  }
#pragma unroll
  for (int j = 0; j < 8; j++) o[j] *= inv;

  // partial reduce across the 4 waves through LDS
  f32x4* ppart = (f32x4*)&s_part[w][lane * 8];
  f32x4 p0 = {o[0], o[1], o[2], o[3]};
  f32x4 p1 = {o[4], o[5], o[6], o[7]};
  ppart[0] = p0;
  ppart[1] = p1;
  __syncthreads();

  const int d0 = t * 2;
  float r0 = s_part[0][d0] + s_part[1][d0] + s_part[2][d0] + s_part[3][d0];
  float r1 = s_part[0][d0 + 1] + s_part[1][d0 + 1] + s_part[2][d0 + 1] + s_part[3][d0 + 1];
  *(unsigned int*)(att + (long)row * 512 + d0) =
      ((unsigned int)f2bf(r1) << 16) | (unsigned int)f2bf(r0);
}

// ---------------- LN1: y = LN(x_f32 + o_bf16) * g + beta, out bf16 --------
__global__ __launch_bounds__(256) void k_ln1(const float* __restrict__ x,
                                             const unsigned short* __restrict__ o,
                                             const float* __restrict__ g,
                                             const float* __restrict__ beta,
                                             unsigned short* __restrict__ y) {
  const int lane = threadIdx.x & 63;
  const int w = threadIdx.x >> 6;
  const long row = (long)blockIdx.x * 4 + w;
  const float4* xp = (const float4*)(x + row * 512 + lane * 8);
  float4 x0 = xp[0], x1 = xp[1];
  short8 ov = *(const short8*)(o + row * 512 + lane * 8);
  float tv[8] = {x0.x, x0.y, x0.z, x0.w, x1.x, x1.y, x1.z, x1.w};
  float s = 0.f, s2 = 0.f;
#pragma unroll
  for (int j = 0; j < 8; j++) {
    tv[j] += bf2f((unsigned short)ov[j]);
    s += tv[j];
    s2 += tv[j] * tv[j];
  }
#pragma unroll
  for (int m = 32; m >= 1; m >>= 1) {
    s += __shfl_xor(s, m, 64);
    s2 += __shfl_xor(s2, m, 64);
  }
  const float mean = s * (1.f / 512.f);
  const float var = s2 * (1.f / 512.f) - mean * mean;
  const float r = rsqrtf(var + 1e-5f);
  const float4* gp = (const float4*)(g + lane * 8);
  const float4* bp = (const float4*)(beta + lane * 8);
  float4 g0 = gp[0], g1v = gp[1], b0 = bp[0], b1 = bp[1];
  float gg[8] = {g0.x, g0.y, g0.z, g0.w, g1v.x, g1v.y, g1v.z, g1v.w};
  float bb[8] = {b0.x, b0.y, b0.z, b0.w, b1.x, b1.y, b1.z, b1.w};
  short8 yv;
#pragma unroll
  for (int j = 0; j < 8; j++) yv[j] = (short)f2bf((tv[j] - mean) * r * gg[j] + bb[j]);
  *(short8*)(y + row * 512 + lane * 8) = yv;
}

// ---------------- LN2: out_f32 = LN(y_bf16 + f_bf16) * g + beta -----------
__global__ __launch_bounds__(256) void k_ln2(const unsigned short* __restrict__ y,
                                             const unsigned short* __restrict__ f,
                                             const float* __restrict__ g,
                                             const float* __restrict__ beta,
                                             float* __restrict__ out) {
  const int lane = threadIdx.x & 63;
  const int w = threadIdx.x >> 6;
  const long row = (long)blockIdx.x * 4 + w;
  short8 yv = *(const short8*)(y + row * 512 + lane * 8);
  short8 fv = *(const short8*)(f + row * 512 + lane * 8);
  float tv[8];
  float s = 0.f, s2 = 0.f;
#pragma unroll
  for (int j = 0; j < 8; j++) {
    tv[j] = bf2f((unsigned short)yv[j]) + bf2f((unsigned short)fv[j]);
    s += tv[j];
    s2 += tv[j] * tv[j];
  }
#pragma unroll
  for (int m = 32; m >= 1; m >>= 1) {
    s += __shfl_xor(s, m, 64);
    s2 += __shfl_xor(s2, m, 64);
  }
  const float mean = s * (1.f / 512.f);
  const float var = s2 * (1.f / 512.f) - mean * mean;
  const float r = rsqrtf(var + 1e-5f);
  const float4* gp = (const float4*)(g + lane * 8);
  const float4* bp = (const float4*)(beta + lane * 8);
  float4 g0 = gp[0], g1v = gp[1], b0 = bp[0], b1 = bp[1];
  float gg[8] = {g0.x, g0.y, g0.z, g0.w, g1v.x, g1v.y, g1v.z, g1v.w};
  float bb[8] = {b0.x, b0.y, b0.z, b0.w, b1.x, b1.y, b1.z, b1.w};
  float ovv[8];
#pragma unroll
  for (int j = 0; j < 8; j++) ovv[j] = (tv[j] - mean) * r * gg[j] + bb[j];
  float4* op = (float4*)(out + row * 512 + lane * 8);
  float4 o0 = {ovv[0], ovv[1], ovv[2], ovv[3]};
  float4 o1 = {ovv[4], ovv[5], ovv[6], ovv[7]};
  op[0] = o0;
  op[1] = o1;
}

extern "C" void kernel_launch(void* const* d_in, const int* in_sizes, int n_in,
                              void* d_out, int out_size, void* d_ws, size_t ws_size,
                              hipStream_t stream) {
  const float* x   = (const float*)d_in[0];
  const float* adj = (const float*)d_in[1];
  const int*   inx = (const int*)d_in[2];
  const float* Wq  = (const float*)d_in[3];
  const float* bq  = (const float*)d_in[4];
  const float* Wk  = (const float*)d_in[5];
  const float* bk  = (const float*)d_in[6];
  const float* Wv  = (const float*)d_in[7];
  const float* bv  = (const float*)d_in[8];
  const float* Wo  = (const float*)d_in[9];
  const float* bo  = (const float*)d_in[10];
  const float* g1  = (const float*)d_in[11];
  const float* be1 = (const float*)d_in[12];
  const float* W1  = (const float*)d_in[13];
  const float* bf1 = (const float*)d_in[14];
  const float* W2  = (const float*)d_in[15];
  const float* bf2 = (const float*)d_in[16];
  const float* g2  = (const float*)d_in[17];
  const float* be2 = (const float*)d_in[18];

  // workspace layout; aliased reuse is stream-ordered-safe:
  // att<-xb (xb dead after G1), h<-qkv (dead after attn), f<-oproj (dead after LN1)
  unsigned short* xb    = (unsigned short*)d_ws;        // 8192*512 (f16)
  unsigned short* wqkvt = xb + 4194304;                 // 1536*512 (f16, B^T)
  unsigned short* wot   = wqkvt + 786432;               // 512*512 (bf16)
  unsigned short* w1t   = wot + 262144;                 // 768*512 (bf16)
  unsigned short* w2t   = w1t + 393216;                 // 512*768 (bf16)
  unsigned short* qkv   = w2t + 393216;                 // 8192*1536 (f16)
  unsigned short* oproj = qkv + 12582912;               // 8192*512 (bf16)
  unsigned short* y     = oproj + 4194304;              // 8192*512 (bf16)
  float*          bqkv  = (float*)(y + 4194304);        // 1536 f32
  unsigned short* att   = xb;                           // bf16
  unsigned short* h     = qkv;                          // bf16
  unsigned short* f     = oproj;                        // bf16

  dim3 tb(32, 8);
  k_cvt<1><<<2048, 256, 0, stream>>>(x, xb, 8192 * 512 / 8);
  k_tpose<1><<<dim3(16, 16), tb, 0, stream>>>(Wq, wqkvt, 512, 512);
  k_tpose<1><<<dim3(16, 16), tb, 0, stream>>>(Wk, wqkvt + 512L * 512, 512, 512);
  k_tpose<1><<<dim3(16, 16), tb, 0, stream>>>(Wv, wqkvt + 1024L * 512, 512, 512);
  k_tpose<0><<<dim3(16, 16), tb, 0, stream>>>(Wo, wot, 512, 512);
  k_tpose<0><<<dim3(24, 16), tb, 0, stream>>>(W1, w1t, 512, 768);
  k_tpose<0><<<dim3(16, 24), tb, 0, stream>>>(W2, w2t, 768, 512);
  k_packb<<<6, 256, 0, stream>>>(bq, bk, bv, bqkv);

  // G1: qkv = x @ [Wq|Wk|Wv] + b   (fp16)
  k_gemm<0, 1><<<dim3(12, 64), 256, 0, stream>>>(xb, wqkvt, bqkv, qkv, 8192, 1536, 512);
  // attention (pre-Wo output, bf16)
  k_attn<<<8192, 256, 0, stream>>>(qkv, adj, inx, att);
  // G2: oproj = relu(att @ Wo + bo)
  k_gemm<1, 0><<<dim3(4, 64), 256, 0, stream>>>(att, wot, bo, oproj, 8192, 512, 512);
  // y = LN(x + oproj)
  k_ln1<<<2048, 256, 0, stream>>>(x, oproj, g1, be1, y);
  // G3: h = relu(y @ W1 + bf1)
  k_gemm<1, 0><<<dim3(6, 64), 256, 0, stream>>>(y, w1t, bf1, h, 8192, 768, 512);
  // G4: f = h @ W2 + bf2
  k_gemm<0, 0><<<dim3(4, 64), 256, 0, stream>>>(h, w2t, bf2, f, 8192, 512, 768);
  // out = LN(y + f)
  k_ln2<<<2048, 256, 0, stream>>>(y, f, g2, be2, (float*)d_out);
}

// Round 5
// 137.112 us; speedup vs baseline: 1.3712x; 1.0882x over previous
//
#include <hip/hip_runtime.h>
#include <stdint.h>

typedef __attribute__((ext_vector_type(8))) short short8;
typedef __attribute__((ext_vector_type(4))) float f32x4;
typedef __attribute__((ext_vector_type(2))) _Float16 h2;
typedef __attribute__((ext_vector_type(8))) _Float16 half8;

static __device__ __forceinline__ unsigned short f2bf(float f) {
  unsigned int u = __float_as_uint(f);
  u += 0x7FFFu + ((u >> 16) & 1u);
  return (unsigned short)(u >> 16);
}
static __device__ __forceinline__ float bf2f(unsigned short h) {
  return __uint_as_float(((unsigned int)h) << 16);
}
static __device__ __forceinline__ unsigned short f2h(float f) {
  _Float16 h = (_Float16)f;
  return __builtin_bit_cast(unsigned short, h);
}
static __device__ __forceinline__ float hdot2(unsigned int a, unsigned int b, float c) {
  return __builtin_amdgcn_fdot2(__builtin_bit_cast(h2, a), __builtin_bit_cast(h2, b), c, false);
}

#define GLD16(gp, lp) __builtin_amdgcn_global_load_lds( \
    (__attribute__((address_space(1))) void*)(gp), \
    (__attribute__((address_space(3))) void*)(lp), 16, 0, 0)

// ---------------- fp32 -> f16/bf16 elementwise (8 per thread) -------------
template <int F16>
__global__ __launch_bounds__(256) void k_cvt(const float* __restrict__ in,
                                             unsigned short* __restrict__ out,
                                             int n8) {
  int i = blockIdx.x * 256 + threadIdx.x;
  if (i >= n8) return;
  const float4* p = (const float4*)in + (long)i * 2;
  float4 a = p[0], b = p[1];
  short8 v;
  if (F16) {
    v[0] = (short)f2h(a.x); v[1] = (short)f2h(a.y);
    v[2] = (short)f2h(a.z); v[3] = (short)f2h(a.w);
    v[4] = (short)f2h(b.x); v[5] = (short)f2h(b.y);
    v[6] = (short)f2h(b.z); v[7] = (short)f2h(b.w);
  } else {
    v[0] = (short)f2bf(a.x); v[1] = (short)f2bf(a.y);
    v[2] = (short)f2bf(a.z); v[3] = (short)f2bf(a.w);
    v[4] = (short)f2bf(b.x); v[5] = (short)f2bf(b.y);
    v[6] = (short)f2bf(b.z); v[7] = (short)f2bf(b.w);
  }
  *(short8*)(out + (long)i * 8) = v;
}

// ------------- ALL weight transposes in one launch (1792 tiles) -----------
// fp32 [R][C] -> f16/bf16 [C][R], 32x32 tiles, block dim (32,8).
__global__ __launch_bounds__(256) void k_tpose_all(
    const float* __restrict__ Wq, const float* __restrict__ Wk,
    const float* __restrict__ Wv, const float* __restrict__ Wo,
    const float* __restrict__ W1, const float* __restrict__ W2,
    unsigned short* __restrict__ wqkvt, unsigned short* __restrict__ wot,
    unsigned short* __restrict__ w1t, unsigned short* __restrict__ w2t) {
  __shared__ float tile[32][33];
  const int bid = blockIdx.x;
  const float* src;
  unsigned short* dst;
  int R, C, f16, local;
  if (bid < 768) {            // Wq, Wk, Wv -> wqkvt (f16), 256 tiles each
    const int m = bid >> 8;
    src = m == 0 ? Wq : (m == 1 ? Wk : Wv);
    dst = wqkvt + (long)m * 512 * 512;
    R = 512; C = 512; f16 = 1; local = bid & 255;
  } else if (bid < 1024) {    // Wo (bf16)
    src = Wo; dst = wot; R = 512; C = 512; f16 = 0; local = bid - 768;
  } else if (bid < 1408) {    // W1: [512][768] (bf16)
    src = W1; dst = w1t; R = 512; C = 768; f16 = 0; local = bid - 1024;
  } else {                    // W2: [768][512] (bf16)
    src = W2; dst = w2t; R = 768; C = 512; f16 = 0; local = bid - 1408;
  }
  const int ntx = C >> 5;
  const int c0 = (local % ntx) << 5;
  const int r0 = (local / ntx) << 5;
  const int tx = threadIdx.x, ty = threadIdx.y;
#pragma unroll
  for (int i = 0; i < 4; i++)
    tile[ty + i * 8][tx] = src[(long)(r0 + ty + i * 8) * C + c0 + tx];
  __syncthreads();
#pragma unroll
  for (int i = 0; i < 4; i++) {
    float v = tile[tx][ty + i * 8];
    dst[(long)(c0 + ty + i * 8) * R + r0 + tx] = f16 ? f2h(v) : f2bf(v);
  }
}

// ---------------- 16-bit MFMA GEMM: C[M,N] = A[M,K] @ Bt[N,K]^T + bias ----
// 128x128 tile, BK=32, 4 waves (2x2), each wave 4x4 fragments of 16x16x32.
// EPI: 0 = bias, 1 = bias + relu. F16: fp16 in/out, else bf16 in/out.
// QKVB: bias selected from 3 arrays by col/512 (fused bq|bk|bv).
template <int EPI, int F16, int QKVB>
__global__ __launch_bounds__(256) void k_gemm(const unsigned short* __restrict__ A,
                                              const unsigned short* __restrict__ Bt,
                                              const float* __restrict__ bias,
                                              const float* __restrict__ bias2,
                                              const float* __restrict__ bias3,
                                              unsigned short* __restrict__ C,
                                              int M, int N, int K) {
  __shared__ unsigned short As[128 * 32];
  __shared__ unsigned short Bs[128 * 32];
  const int t = threadIdx.x;
  const int lane = t & 63;
  const int w = t >> 6;
  const int wr = w >> 1, wc = w & 1;
  const int m0 = blockIdx.y * 128;
  const int n0 = blockIdx.x * 128;

  f32x4 acc[4][4];
#pragma unroll
  for (int mi = 0; mi < 4; mi++)
#pragma unroll
    for (int ni = 0; ni < 4; ni++) {
      f32x4 z = {0.f, 0.f, 0.f, 0.f};
      acc[mi][ni] = z;
    }

  const int c0 = t;
  const int c1 = t + 256;
  const int arow0 = c0 >> 2, acol0 = (c0 & 3) * 8;
  const int arow1 = c1 >> 2, acol1 = (c1 & 3) * 8;

  for (int k0 = 0; k0 < K; k0 += 32) {
    GLD16(A + (long)(m0 + arow0) * K + k0 + acol0, As + (long)c0 * 8);
    GLD16(A + (long)(m0 + arow1) * K + k0 + acol1, As + (long)c1 * 8);
    GLD16(Bt + (long)(n0 + arow0) * K + k0 + acol0, Bs + (long)c0 * 8);
    GLD16(Bt + (long)(n0 + arow1) * K + k0 + acol1, Bs + (long)c1 * 8);
    __syncthreads();

    short8 af[4], bf[4];
#pragma unroll
    for (int mi = 0; mi < 4; mi++)
      af[mi] = *(const short8*)&As[(wr * 64 + mi * 16 + (lane & 15)) * 32 + (lane >> 4) * 8];
#pragma unroll
    for (int ni = 0; ni < 4; ni++)
      bf[ni] = *(const short8*)&Bs[(wc * 64 + ni * 16 + (lane & 15)) * 32 + (lane >> 4) * 8];
#pragma unroll
    for (int mi = 0; mi < 4; mi++)
#pragma unroll
      for (int ni = 0; ni < 4; ni++) {
        if (F16)
          acc[mi][ni] = __builtin_amdgcn_mfma_f32_16x16x32_f16(
              __builtin_bit_cast(half8, af[mi]), __builtin_bit_cast(half8, bf[ni]),
              acc[mi][ni], 0, 0, 0);
        else
          acc[mi][ni] = __builtin_amdgcn_mfma_f32_16x16x32_bf16(af[mi], bf[ni], acc[mi][ni], 0, 0, 0);
      }
    __syncthreads();
  }

  const int lr = (lane >> 4) * 4;
  const int lc = lane & 15;
#pragma unroll
  for (int mi = 0; mi < 4; mi++) {
#pragma unroll
    for (int ni = 0; ni < 4; ni++) {
      const int col = n0 + wc * 64 + ni * 16 + lc;
      float bv;
      if (QKVB)
        bv = col < 512 ? bias[col] : (col < 1024 ? bias2[col - 512] : bias3[col - 1024]);
      else
        bv = bias[col];
#pragma unroll
      for (int r = 0; r < 4; r++) {
        const int row = m0 + wr * 64 + mi * 16 + lr + r;
        float v = acc[mi][ni][r] + bv;
        if (EPI == 1) v = fmaxf(v, 0.f);
        C[(long)row * N + col] = F16 ? f2h(v) : f2bf(v);
      }
    }
  }
}

// ---------------- attention: ONE WAVE per row, no barriers, no LDS --------
// qkv: [8192][1536] f16 (q|k|v). att: [8192][512] bf16.
// Scores: 8 rounds x 4 neighbors (16-lane group each), intra-group reduce,
// then redistribute so lane kk owns score kk. Softmax in shuffles.
// PV: 16 neighbor pairs, full-row coalesced loads, fdot2 with packed weights.
// XCD swizzle: batch b -> XCDs {2b,2b+1} so k/v gathers hit the local L2.
__global__ __launch_bounds__(256) void k_attn(const unsigned short* __restrict__ qkv,
                                              const float* __restrict__ adj,
                                              const int* __restrict__ inxs,
                                              unsigned short* __restrict__ att) {
  const int t = threadIdx.x;
  const int lane = t & 63;
  const int w = t >> 6;
  const int bid = blockIdx.x;
  const int xcd = bid & 7;
  const int b = xcd >> 1;                         // batch 0..3 on XCDs {2b,2b+1}
  const int sub = ((bid >> 3) << 1) | (xcd & 1);  // 0..511, bijective
  const int row = (b << 11) | (sub << 2) | w;
  const long base = (long)b * 2048;
  const int g = lane >> 4;   // score group 0..3
  const int li = lane & 15;  // lane in group
  const int kk = lane & 31;  // score ownership (dup in upper half)

  const int* ix = inxs + (long)row * 32;
  const float* adjrow = adj + (long)row * 2048;

  const int ixv = ix[kk];            // lane kk holds ix[kk]
  const float adjv = adjrow[ixv];    // per-lane gather of adj for own neighbor

  // q chunks: lane li covers uint4 chunks {li, li+16, li+32, li+48}
  const uint4* qp = (const uint4*)(qkv + (long)row * 1536);
  uint4 qc[4];
#pragma unroll
  for (int c = 0; c < 4; c++) qc[c] = qp[li + c * 16];

  // 8 rounds x 4 neighbors: group g computes neighbor 4r+g
  float scr[8];
#pragma unroll
  for (int r = 0; r < 8; r++) {
    const int nb = __shfl(ixv, r * 4 + g, 64);
    const uint4* kp = (const uint4*)(qkv + (base + nb) * 1536 + 512);
    float d = 0.f;
#pragma unroll
    for (int c = 0; c < 4; c++) {
      uint4 kc = kp[li + c * 16];
      d = hdot2(kc.x, qc[c].x, d);
      d = hdot2(kc.y, qc[c].y, d);
      d = hdot2(kc.z, qc[c].z, d);
      d = hdot2(kc.w, qc[c].w, d);
    }
#pragma unroll
    for (int m = 1; m <= 8; m <<= 1) d += __shfl_xor(d, m, 64);
    scr[r] = d;  // all 16 lanes of group g hold neighbor 4r+g's dot
  }

  // redistribute: lane kk takes scr[kk>>2] from lane (kk&3)*16
  const int srcl = (kk & 3) << 4;
  float s = __shfl(scr[0], srcl, 64);
#pragma unroll
  for (int r = 1; r < 8; r++) {
    const float tr = __shfl(scr[r], srcl, 64);
    s = ((kk >> 2) == r) ? tr : s;
  }
  s = s * 0.044194173824159216f + (adjv > 0.f ? 0.f : -1e22f);

  // softmax across the 32 owned scores (both wave halves identical)
  float mx = s;
#pragma unroll
  for (int d = 1; d <= 16; d <<= 1) mx = fmaxf(mx, __shfl_xor(mx, d, 64));
  const float e = __expf(s - mx);
  float ts = e;
#pragma unroll
  for (int d = 1; d <= 16; d <<= 1) ts += __shfl_xor(ts, d, 64);
  const float inv = 1.f / ts;

  // PV: 16 neighbor pairs; each lane covers feats lane*8..lane*8+8
  float o[8] = {0, 0, 0, 0, 0, 0, 0, 0};
#pragma unroll
  for (int p = 0; p < 16; p++) {
    const int u0 = __shfl(ixv, 2 * p, 64);
    const int u1 = __shfl(ixv, 2 * p + 1, 64);
    const uint4 v0c = *(const uint4*)(qkv + (base + u0) * 1536 + 1024 + lane * 8);
    const uint4 v1c = *(const uint4*)(qkv + (base + u1) * 1536 + 1024 + lane * 8);
    const float pe0 = __shfl(e, 2 * p, 64);
    const float pe1 = __shfl(e, 2 * p + 1, 64);
    const unsigned int pp =
        __builtin_bit_cast(unsigned int, __builtin_amdgcn_cvt_pkrtz(pe0, pe1));
    const unsigned int vw0[4] = {v0c.x, v0c.y, v0c.z, v0c.w};
    const unsigned int vw1[4] = {v1c.x, v1c.y, v1c.z, v1c.w};
#pragma unroll
    for (int q = 0; q < 4; q++) {
      const unsigned int even = __builtin_amdgcn_perm(vw1[q], vw0[q], 0x05040100u);
      const unsigned int odd  = __builtin_amdgcn_perm(vw1[q], vw0[q], 0x07060302u);
      o[2 * q]     = hdot2(even, pp, o[2 * q]);
      o[2 * q + 1] = hdot2(odd,  pp, o[2 * q + 1]);
    }
  }

  short8 ov;
#pragma unroll
  for (int j = 0; j < 8; j++) ov[j] = (short)f2bf(o[j] * inv);
  *(short8*)(att + (long)row * 512 + lane * 8) = ov;
}

// ---------------- LN1: y = LN(x_f32 + o_bf16) * g + beta, out bf16 --------
__global__ __launch_bounds__(256) void k_ln1(const float* __restrict__ x,
                                             const unsigned short* __restrict__ o,
                                             const float* __restrict__ g,
                                             const float* __restrict__ beta,
                                             unsigned short* __restrict__ y) {
  const int lane = threadIdx.x & 63;
  const int w = threadIdx.x >> 6;
  const long row = (long)blockIdx.x * 4 + w;
  const float4* xp = (const float4*)(x + row * 512 + lane * 8);
  float4 x0 = xp[0], x1 = xp[1];
  short8 ov = *(const short8*)(o + row * 512 + lane * 8);
  float tv[8] = {x0.x, x0.y, x0.z, x0.w, x1.x, x1.y, x1.z, x1.w};
  float s = 0.f, s2 = 0.f;
#pragma unroll
  for (int j = 0; j < 8; j++) {
    tv[j] += bf2f((unsigned short)ov[j]);
    s += tv[j];
    s2 += tv[j] * tv[j];
  }
#pragma unroll
  for (int m = 32; m >= 1; m >>= 1) {
    s += __shfl_xor(s, m, 64);
    s2 += __shfl_xor(s2, m, 64);
  }
  const float mean = s * (1.f / 512.f);
  const float var = s2 * (1.f / 512.f) - mean * mean;
  const float r = rsqrtf(var + 1e-5f);
  const float4* gp = (const float4*)(g + lane * 8);
  const float4* bp = (const float4*)(beta + lane * 8);
  float4 g0 = gp[0], g1v = gp[1], b0 = bp[0], b1 = bp[1];
  float gg[8] = {g0.x, g0.y, g0.z, g0.w, g1v.x, g1v.y, g1v.z, g1v.w};
  float bb[8] = {b0.x, b0.y, b0.z, b0.w, b1.x, b1.y, b1.z, b1.w};
  short8 yv;
#pragma unroll
  for (int j = 0; j < 8; j++) yv[j] = (short)f2bf((tv[j] - mean) * r * gg[j] + bb[j]);
  *(short8*)(y + row * 512 + lane * 8) = yv;
}

// ---------------- LN2: out_f32 = LN(y_bf16 + f_bf16) * g + beta -----------
__global__ __launch_bounds__(256) void k_ln2(const unsigned short* __restrict__ y,
                                             const unsigned short* __restrict__ f,
                                             const float* __restrict__ g,
                                             const float* __restrict__ beta,
                                             float* __restrict__ out) {
  const int lane = threadIdx.x & 63;
  const int w = threadIdx.x >> 6;
  const long row = (long)blockIdx.x * 4 + w;
  short8 yv = *(const short8*)(y + row * 512 + lane * 8);
  short8 fv = *(const short8*)(f + row * 512 + lane * 8);
  float tv[8];
  float s = 0.f, s2 = 0.f;
#pragma unroll
  for (int j = 0; j < 8; j++) {
    tv[j] = bf2f((unsigned short)yv[j]) + bf2f((unsigned short)fv[j]);
    s += tv[j];
    s2 += tv[j] * tv[j];
  }
#pragma unroll
  for (int m = 32; m >= 1; m >>= 1) {
    s += __shfl_xor(s, m, 64);
    s2 += __shfl_xor(s2, m, 64);
  }
  const float mean = s * (1.f / 512.f);
  const float var = s2 * (1.f / 512.f) - mean * mean;
  const float r = rsqrtf(var + 1e-5f);
  const float4* gp = (const float4*)(g + lane * 8);
  const float4* bp = (const float4*)(beta + lane * 8);
  float4 g0 = gp[0], g1v = gp[1], b0 = bp[0], b1 = bp[1];
  float gg[8] = {g0.x, g0.y, g0.z, g0.w, g1v.x, g1v.y, g1v.z, g1v.w};
  float bb[8] = {b0.x, b0.y, b0.z, b0.w, b1.x, b1.y, b1.z, b1.w};
  float ovv[8];
#pragma unroll
  for (int j = 0; j < 8; j++) ovv[j] = (tv[j] - mean) * r * gg[j] + bb[j];
  float4* op = (float4*)(out + row * 512 + lane * 8);
  float4 o0 = {ovv[0], ovv[1], ovv[2], ovv[3]};
  float4 o1 = {ovv[4], ovv[5], ovv[6], ovv[7]};
  op[0] = o0;
  op[1] = o1;
}

extern "C" void kernel_launch(void* const* d_in, const int* in_sizes, int n_in,
                              void* d_out, int out_size, void* d_ws, size_t ws_size,
                              hipStream_t stream) {
  const float* x   = (const float*)d_in[0];
  const float* adj = (const float*)d_in[1];
  const int*   inx = (const int*)d_in[2];
  const float* Wq  = (const float*)d_in[3];
  const float* bq  = (const float*)d_in[4];
  const float* Wk  = (const float*)d_in[5];
  const float* bk  = (const float*)d_in[6];
  const float* Wv  = (const float*)d_in[7];
  const float* bv  = (const float*)d_in[8];
  const float* Wo  = (const float*)d_in[9];
  const float* bo  = (const float*)d_in[10];
  const float* g1  = (const float*)d_in[11];
  const float* be1 = (const float*)d_in[12];
  const float* W1  = (const float*)d_in[13];
  const float* bf1 = (const float*)d_in[14];
  const float* W2  = (const float*)d_in[15];
  const float* bf2 = (const float*)d_in[16];
  const float* g2  = (const float*)d_in[17];
  const float* be2 = (const float*)d_in[18];

  // workspace layout; aliased reuse is stream-ordered-safe:
  // att<-xb (xb dead after G1), h<-qkv (dead after attn), f<-oproj (dead after LN1)
  unsigned short* xb    = (unsigned short*)d_ws;        // 8192*512 (f16)
  unsigned short* wqkvt = xb + 4194304;                 // 1536*512 (f16, B^T)
  unsigned short* wot   = wqkvt + 786432;               // 512*512 (bf16)
  unsigned short* w1t   = wot + 262144;                 // 768*512 (bf16)
  unsigned short* w2t   = w1t + 393216;                 // 512*768 (bf16)
  unsigned short* qkv   = w2t + 393216;                 // 8192*1536 (f16)
  unsigned short* oproj = qkv + 12582912;               // 8192*512 (bf16)
  unsigned short* y     = oproj + 4194304;              // 8192*512 (bf16)
  unsigned short* att   = xb;                           // bf16
  unsigned short* h     = qkv;                          // bf16
  unsigned short* f     = oproj;                        // bf16

  k_cvt<1><<<2048, 256, 0, stream>>>(x, xb, 8192 * 512 / 8);
  k_tpose_all<<<1792, dim3(32, 8), 0, stream>>>(Wq, Wk, Wv, Wo, W1, W2,
                                                wqkvt, wot, w1t, w2t);

  // G1: qkv = x @ [Wq|Wk|Wv] + [bq|bk|bv]   (fp16)
  k_gemm<0, 1, 1><<<dim3(12, 64), 256, 0, stream>>>(xb, wqkvt, bq, bk, bv, qkv, 8192, 1536, 512);
  // attention (pre-Wo output, bf16)
  k_attn<<<2048, 256, 0, stream>>>(qkv, adj, inx, att);
  // G2: oproj = relu(att @ Wo + bo)
  k_gemm<1, 0, 0><<<dim3(4, 64), 256, 0, stream>>>(att, wot, bo, bo, bo, oproj, 8192, 512, 512);
  // y = LN(x + oproj)
  k_ln1<<<2048, 256, 0, stream>>>(x, oproj, g1, be1, y);
  // G3: h = relu(y @ W1 + bf1)
  k_gemm<1, 0, 0><<<dim3(6, 64), 256, 0, stream>>>(y, w1t, bf1, bf1, bf1, h, 8192, 768, 512);
  // G4: f = h @ W2 + bf2
  k_gemm<0, 0, 0><<<dim3(4, 64), 256, 0, stream>>>(h, w2t, bf2, bf2, bf2, f, 8192, 512, 768);
  // out = LN(y + f)
  k_ln2<<<2048, 256, 0, stream>>>(y, f, g2, be2, (float*)d_out);
}

// Round 6
// 126.560 us; speedup vs baseline: 1.4855x; 1.0834x over previous
//
#include <hip/hip_runtime.h>
#include <stdint.h>

typedef __attribute__((ext_vector_type(8))) short short8;
typedef __attribute__((ext_vector_type(4))) float f32x4;
typedef __attribute__((ext_vector_type(2))) _Float16 h2;
typedef __attribute__((ext_vector_type(8))) _Float16 half8;

static __device__ __forceinline__ unsigned short f2bf(float f) {
  unsigned int u = __float_as_uint(f);
  u += 0x7FFFu + ((u >> 16) & 1u);
  return (unsigned short)(u >> 16);
}
static __device__ __forceinline__ float bf2f(unsigned short h) {
  return __uint_as_float(((unsigned int)h) << 16);
}
static __device__ __forceinline__ unsigned short f2h(float f) {
  _Float16 h = (_Float16)f;
  return __builtin_bit_cast(unsigned short, h);
}
static __device__ __forceinline__ float hdot2(unsigned int a, unsigned int b, float c) {
  return __builtin_amdgcn_fdot2(__builtin_bit_cast(h2, a), __builtin_bit_cast(h2, b), c, false);
}

#define GLD16(gp, lp) __builtin_amdgcn_global_load_lds( \
    (__attribute__((address_space(1))) void*)(gp), \
    (__attribute__((address_space(3))) void*)(lp), 16, 0, 0)

// ---------------- fp32 -> f16/bf16 elementwise (8 per thread) -------------
template <int F16>
__global__ __launch_bounds__(256) void k_cvt(const float* __restrict__ in,
                                             unsigned short* __restrict__ out,
                                             int n8) {
  int i = blockIdx.x * 256 + threadIdx.x;
  if (i >= n8) return;
  const float4* p = (const float4*)in + (long)i * 2;
  float4 a = p[0], b = p[1];
  short8 v;
  if (F16) {
    v[0] = (short)f2h(a.x); v[1] = (short)f2h(a.y);
    v[2] = (short)f2h(a.z); v[3] = (short)f2h(a.w);
    v[4] = (short)f2h(b.x); v[5] = (short)f2h(b.y);
    v[6] = (short)f2h(b.z); v[7] = (short)f2h(b.w);
  } else {
    v[0] = (short)f2bf(a.x); v[1] = (short)f2bf(a.y);
    v[2] = (short)f2bf(a.z); v[3] = (short)f2bf(a.w);
    v[4] = (short)f2bf(b.x); v[5] = (short)f2bf(b.y);
    v[6] = (short)f2bf(b.z); v[7] = (short)f2bf(b.w);
  }
  *(short8*)(out + (long)i * 8) = v;
}

// ------------- ALL weight transposes in one launch (1792 tiles) -----------
__global__ __launch_bounds__(256) void k_tpose_all(
    const float* __restrict__ Wq, const float* __restrict__ Wk,
    const float* __restrict__ Wv, const float* __restrict__ Wo,
    const float* __restrict__ W1, const float* __restrict__ W2,
    unsigned short* __restrict__ wqkvt, unsigned short* __restrict__ wot,
    unsigned short* __restrict__ w1t, unsigned short* __restrict__ w2t) {
  __shared__ float tile[32][33];
  const int bid = blockIdx.x;
  const float* src;
  unsigned short* dst;
  int R, C, f16, local;
  if (bid < 768) {
    const int m = bid >> 8;
    src = m == 0 ? Wq : (m == 1 ? Wk : Wv);
    dst = wqkvt + (long)m * 512 * 512;
    R = 512; C = 512; f16 = 1; local = bid & 255;
  } else if (bid < 1024) {
    src = Wo; dst = wot; R = 512; C = 512; f16 = 0; local = bid - 768;
  } else if (bid < 1408) {
    src = W1; dst = w1t; R = 512; C = 768; f16 = 0; local = bid - 1024;
  } else {
    src = W2; dst = w2t; R = 768; C = 512; f16 = 0; local = bid - 1408;
  }
  const int ntx = C >> 5;
  const int c0 = (local % ntx) << 5;
  const int r0 = (local / ntx) << 5;
  const int tx = threadIdx.x, ty = threadIdx.y;
#pragma unroll
  for (int i = 0; i < 4; i++)
    tile[ty + i * 8][tx] = src[(long)(r0 + ty + i * 8) * C + c0 + tx];
  __syncthreads();
#pragma unroll
  for (int i = 0; i < 4; i++) {
    float v = tile[tx][ty + i * 8];
    dst[(long)(c0 + ty + i * 8) * R + r0 + tx] = f16 ? f2h(v) : f2bf(v);
  }
}

// ------- 16-bit MFMA GEMM, 128x64 tile, BK=64, dbuf + counted vmcnt -------
// C[M,N] = A[M,K] @ Bt[N,K]^T + bias. 4 waves (2Mx2N), wave = 64x32 (4x2 frags).
// LDS rows are 128B: XOR-swizzle 16B chunks by (row&7); global source is
// inverse-swizzled so GLD16's linear LDS write lands pre-swizzled (rule 21).
// EPI: 0 = bias, 1 = bias+relu. F16: fp16 in/out else bf16. QKVB: bias|3-way.
template <int EPI, int F16, int QKVB>
__global__ __launch_bounds__(256) void k_gemm(const unsigned short* __restrict__ A,
                                              const unsigned short* __restrict__ Bt,
                                              const float* __restrict__ bias,
                                              const float* __restrict__ bias2,
                                              const float* __restrict__ bias3,
                                              unsigned short* __restrict__ C,
                                              int M, int N, int K) {
  __shared__ unsigned short As[2][128 * 64];
  __shared__ unsigned short Bs[2][64 * 64];
  const int t = threadIdx.x;
  const int lane = t & 63;
  const int w = t >> 6;
  const int wr = w >> 1, wc = w & 1;
  const int m0 = blockIdx.y * 128;
  const int n0 = blockIdx.x * 64;

  f32x4 acc[4][2];
#pragma unroll
  for (int mi = 0; mi < 4; mi++)
#pragma unroll
    for (int ni = 0; ni < 2; ni++) {
      f32x4 z = {0.f, 0.f, 0.f, 0.f};
      acc[mi][ni] = z;
    }

  // stage one BK=64 tile into buffer `buf` (6 GLD16 per thread)
  auto stage = [&](int buf, int k0) {
#pragma unroll
    for (int i = 0; i < 4; i++) {
      const int c = t + i * 256;
      const int r = c >> 3, j = c & 7;
      GLD16(A + (long)(m0 + r) * K + k0 + ((j ^ (r & 7)) << 3), &As[buf][c * 8]);
    }
#pragma unroll
    for (int i = 0; i < 2; i++) {
      const int c = t + i * 256;
      const int r = c >> 3, j = c & 7;
      GLD16(Bt + (long)(n0 + r) * K + k0 + ((j ^ (r & 7)) << 3), &Bs[buf][c * 8]);
    }
  };

  const int nt = K >> 6;
  stage(0, 0);
  for (int tt = 0; tt < nt; ++tt) {
    const int cur = tt & 1;
    if (tt + 1 < nt) {
      stage(cur ^ 1, (tt + 1) << 6);
      asm volatile("s_waitcnt vmcnt(6)" ::: "memory");  // current tile landed; next 6 in flight
    } else {
      asm volatile("s_waitcnt vmcnt(0)" ::: "memory");
    }
    __builtin_amdgcn_s_barrier();

#pragma unroll
    for (int kk = 0; kk < 2; kk++) {
      short8 af[4], bf[2];
#pragma unroll
      for (int mi = 0; mi < 4; mi++) {
        const int r = wr * 64 + mi * 16 + (lane & 15);
        const int jj = (kk << 2) + (lane >> 4);
        af[mi] = *(const short8*)&As[cur][r * 64 + ((jj ^ (r & 7)) << 3)];
      }
#pragma unroll
      for (int ni = 0; ni < 2; ni++) {
        const int r = wc * 32 + ni * 16 + (lane & 15);
        const int jj = (kk << 2) + (lane >> 4);
        bf[ni] = *(const short8*)&Bs[cur][r * 64 + ((jj ^ (r & 7)) << 3)];
      }
#pragma unroll
      for (int mi = 0; mi < 4; mi++)
#pragma unroll
        for (int ni = 0; ni < 2; ni++) {
          if (F16)
            acc[mi][ni] = __builtin_amdgcn_mfma_f32_16x16x32_f16(
                __builtin_bit_cast(half8, af[mi]), __builtin_bit_cast(half8, bf[ni]),
                acc[mi][ni], 0, 0, 0);
          else
            acc[mi][ni] = __builtin_amdgcn_mfma_f32_16x16x32_bf16(af[mi], bf[ni], acc[mi][ni], 0, 0, 0);
        }
    }
    asm volatile("s_waitcnt lgkmcnt(0)" ::: "memory");  // my ds_reads done before others overwrite
    __builtin_amdgcn_s_barrier();
  }

  const int lr = (lane >> 4) * 4;
  const int lc = lane & 15;
#pragma unroll
  for (int mi = 0; mi < 4; mi++) {
#pragma unroll
    for (int ni = 0; ni < 2; ni++) {
      const int col = n0 + wc * 32 + ni * 16 + lc;
      float bv;
      if (QKVB)
        bv = col < 512 ? bias[col] : (col < 1024 ? bias2[col - 512] : bias3[col - 1024]);
      else
        bv = bias[col];
#pragma unroll
      for (int r = 0; r < 4; r++) {
        const int row = m0 + wr * 64 + mi * 16 + lr + r;
        float v = acc[mi][ni][r] + bv;
        if (EPI == 1) v = fmaxf(v, 0.f);
        C[(long)row * N + col] = F16 ? f2h(v) : f2bf(v);
      }
    }
  }
}

// ---------------- attention: ONE WAVE per row, no barriers, no LDS --------
// qkv: [8192][1536] f16 (q|k|v). att: [8192][512] bf16.
// 1-deep software prefetch on k-rounds and v-pairs for memory-level parallelism.
__global__ __launch_bounds__(256) void k_attn(const unsigned short* __restrict__ qkv,
                                              const float* __restrict__ adj,
                                              const int* __restrict__ inxs,
                                              unsigned short* __restrict__ att) {
  const int t = threadIdx.x;
  const int lane = t & 63;
  const int w = t >> 6;
  const int bid = blockIdx.x;
  const int xcd = bid & 7;
  const int b = xcd >> 1;
  const int sub = ((bid >> 3) << 1) | (xcd & 1);
  const int row = (b << 11) | (sub << 2) | w;
  const long base = (long)b * 2048;
  const int g = lane >> 4;
  const int li = lane & 15;
  const int kk = lane & 31;

  const int* ix = inxs + (long)row * 32;
  const float* adjrow = adj + (long)row * 2048;

  const int ixv = ix[kk];
  const float adjv = adjrow[ixv];

  const uint4* qp = (const uint4*)(qkv + (long)row * 1536);
  uint4 qc[4];
#pragma unroll
  for (int c = 0; c < 4; c++) qc[c] = qp[li + c * 16];

  // scores: 8 rounds x 4 neighbors, 1-round-ahead k prefetch
  float scr[8];
  uint4 ka[4], kb[4];
  {
    const int nb = __shfl(ixv, g, 64);
    const uint4* kp = (const uint4*)(qkv + (base + nb) * 1536 + 512);
#pragma unroll
    for (int c = 0; c < 4; c++) ka[c] = kp[li + c * 16];
  }
#pragma unroll
  for (int r = 0; r < 8; r++) {
    uint4* curk = (r & 1) ? kb : ka;
    uint4* nxtk = (r & 1) ? ka : kb;
    if (r < 7) {
      const int nb = __shfl(ixv, (r + 1) * 4 + g, 64);
      const uint4* kp = (const uint4*)(qkv + (base + nb) * 1536 + 512);
#pragma unroll
      for (int c = 0; c < 4; c++) nxtk[c] = kp[li + c * 16];
    }
    float d = 0.f;
#pragma unroll
    for (int c = 0; c < 4; c++) {
      d = hdot2(curk[c].x, qc[c].x, d);
      d = hdot2(curk[c].y, qc[c].y, d);
      d = hdot2(curk[c].z, qc[c].z, d);
      d = hdot2(curk[c].w, qc[c].w, d);
    }
#pragma unroll
    for (int m = 1; m <= 8; m <<= 1) d += __shfl_xor(d, m, 64);
    scr[r] = d;
  }

  // redistribute: lane kk takes scr[kk>>2] from lane (kk&3)*16
  const int srcl = (kk & 3) << 4;
  float s = __shfl(scr[0], srcl, 64);
#pragma unroll
  for (int r = 1; r < 8; r++) {
    const float tr = __shfl(scr[r], srcl, 64);
    s = ((kk >> 2) == r) ? tr : s;
  }
  s = s * 0.044194173824159216f + (adjv > 0.f ? 0.f : -1e22f);

  // softmax across 32 owned scores
  float mx = s;
#pragma unroll
  for (int d = 1; d <= 16; d <<= 1) mx = fmaxf(mx, __shfl_xor(mx, d, 64));
  const float e = __expf(s - mx);
  float ts = e;
#pragma unroll
  for (int d = 1; d <= 16; d <<= 1) ts += __shfl_xor(ts, d, 64);
  const float inv = 1.f / ts;

  // PV: 16 neighbor pairs, 1-pair-ahead prefetch
  float o[8] = {0, 0, 0, 0, 0, 0, 0, 0};
  uint4 va0, va1, vb0, vb1;
  {
    const int u0 = __shfl(ixv, 0, 64);
    const int u1 = __shfl(ixv, 1, 64);
    va0 = *(const uint4*)(qkv + (base + u0) * 1536 + 1024 + lane * 8);
    va1 = *(const uint4*)(qkv + (base + u1) * 1536 + 1024 + lane * 8);
  }
#pragma unroll
  for (int p = 0; p < 16; p++) {
    const uint4 v0c = (p & 1) ? vb0 : va0;
    const uint4 v1c = (p & 1) ? vb1 : va1;
    if (p < 15) {
      const int u0 = __shfl(ixv, 2 * p + 2, 64);
      const int u1 = __shfl(ixv, 2 * p + 3, 64);
      const uint4 n0 = *(const uint4*)(qkv + (base + u0) * 1536 + 1024 + lane * 8);
      const uint4 n1 = *(const uint4*)(qkv + (base + u1) * 1536 + 1024 + lane * 8);
      if (p & 1) { va0 = n0; va1 = n1; } else { vb0 = n0; vb1 = n1; }
    }
    const float pe0 = __shfl(e, 2 * p, 64);
    const float pe1 = __shfl(e, 2 * p + 1, 64);
    const unsigned int pp =
        __builtin_bit_cast(unsigned int, __builtin_amdgcn_cvt_pkrtz(pe0, pe1));
    const unsigned int vw0[4] = {v0c.x, v0c.y, v0c.z, v0c.w};
    const unsigned int vw1[4] = {v1c.x, v1c.y, v1c.z, v1c.w};
#pragma unroll
    for (int q = 0; q < 4; q++) {
      const unsigned int even = __builtin_amdgcn_perm(vw1[q], vw0[q], 0x05040100u);
      const unsigned int odd  = __builtin_amdgcn_perm(vw1[q], vw0[q], 0x07060302u);
      o[2 * q]     = hdot2(even, pp, o[2 * q]);
      o[2 * q + 1] = hdot2(odd,  pp, o[2 * q + 1]);
    }
  }

  short8 ov;
#pragma unroll
  for (int j = 0; j < 8; j++) ov[j] = (short)f2bf(o[j] * inv);
  *(short8*)(att + (long)row * 512 + lane * 8) = ov;
}

// ---------------- LN1: y = LN(x_f32 + o_bf16) * g + beta, out bf16 --------
__global__ __launch_bounds__(256) void k_ln1(const float* __restrict__ x,
                                             const unsigned short* __restrict__ o,
                                             const float* __restrict__ g,
                                             const float* __restrict__ beta,
                                             unsigned short* __restrict__ y) {
  const int lane = threadIdx.x & 63;
  const int w = threadIdx.x >> 6;
  const long row = (long)blockIdx.x * 4 + w;
  const float4* xp = (const float4*)(x + row * 512 + lane * 8);
  float4 x0 = xp[0], x1 = xp[1];
  short8 ov = *(const short8*)(o + row * 512 + lane * 8);
  float tv[8] = {x0.x, x0.y, x0.z, x0.w, x1.x, x1.y, x1.z, x1.w};
  float s = 0.f, s2 = 0.f;
#pragma unroll
  for (int j = 0; j < 8; j++) {
    tv[j] += bf2f((unsigned short)ov[j]);
    s += tv[j];
    s2 += tv[j] * tv[j];
  }
#pragma unroll
  for (int m = 32; m >= 1; m >>= 1) {
    s += __shfl_xor(s, m, 64);
    s2 += __shfl_xor(s2, m, 64);
  }
  const float mean = s * (1.f / 512.f);
  const float var = s2 * (1.f / 512.f) - mean * mean;
  const float r = rsqrtf(var + 1e-5f);
  const float4* gp = (const float4*)(g + lane * 8);
  const float4* bp = (const float4*)(beta + lane * 8);
  float4 g0 = gp[0], g1v = gp[1], b0 = bp[0], b1 = bp[1];
  float gg[8] = {g0.x, g0.y, g0.z, g0.w, g1v.x, g1v.y, g1v.z, g1v.w};
  float bb[8] = {b0.x, b0.y, b0.z, b0.w, b1.x, b1.y, b1.z, b1.w};
  short8 yv;
#pragma unroll
  for (int j = 0; j < 8; j++) yv[j] = (short)f2bf((tv[j] - mean) * r * gg[j] + bb[j]);
  *(short8*)(y + row * 512 + lane * 8) = yv;
}

// ---------------- LN2: out_f32 = LN(y_bf16 + f_bf16) * g + beta -----------
__global__ __launch_bounds__(256) void k_ln2(const unsigned short* __restrict__ y,
                                             const unsigned short* __restrict__ f,
                                             const float* __restrict__ g,
                                             const float* __restrict__ beta,
                                             float* __restrict__ out) {
  const int lane = threadIdx.x & 63;
  const int w = threadIdx.x >> 6;
  const long row = (long)blockIdx.x * 4 + w;
  short8 yv = *(const short8*)(y + row * 512 + lane * 8);
  short8 fv = *(const short8*)(f + row * 512 + lane * 8);
  float tv[8];
  float s = 0.f, s2 = 0.f;
#pragma unroll
  for (int j = 0; j < 8; j++) {
    tv[j] = bf2f((unsigned short)yv[j]) + bf2f((unsigned short)fv[j]);
    s += tv[j];
    s2 += tv[j] * tv[j];
  }
#pragma unroll
  for (int m = 32; m >= 1; m >>= 1) {
    s += __shfl_xor(s, m, 64);
    s2 += __shfl_xor(s2, m, 64);
  }
  const float mean = s * (1.f / 512.f);
  const float var = s2 * (1.f / 512.f) - mean * mean;
  const float r = rsqrtf(var + 1e-5f);
  const float4* gp = (const float4*)(g + lane * 8);
  const float4* bp = (const float4*)(beta + lane * 8);
  float4 g0 = gp[0], g1v = gp[1], b0 = bp[0], b1 = bp[1];
  float gg[8] = {g0.x, g0.y, g0.z, g0.w, g1v.x, g1v.y, g1v.z, g1v.w};
  float bb[8] = {b0.x, b0.y, b0.z, b0.w, b1.x, b1.y, b1.z, b1.w};
  float ovv[8];
#pragma unroll
  for (int j = 0; j < 8; j++) ovv[j] = (tv[j] - mean) * r * gg[j] + bb[j];
  float4* op = (float4*)(out + row * 512 + lane * 8);
  float4 o0 = {ovv[0], ovv[1], ovv[2], ovv[3]};
  float4 o1 = {ovv[4], ovv[5], ovv[6], ovv[7]};
  op[0] = o0;
  op[1] = o1;
}

extern "C" void kernel_launch(void* const* d_in, const int* in_sizes, int n_in,
                              void* d_out, int out_size, void* d_ws, size_t ws_size,
                              hipStream_t stream) {
  const float* x   = (const float*)d_in[0];
  const float* adj = (const float*)d_in[1];
  const int*   inx = (const int*)d_in[2];
  const float* Wq  = (const float*)d_in[3];
  const float* bq  = (const float*)d_in[4];
  const float* Wk  = (const float*)d_in[5];
  const float* bk  = (const float*)d_in[6];
  const float* Wv  = (const float*)d_in[7];
  const float* bv  = (const float*)d_in[8];
  const float* Wo  = (const float*)d_in[9];
  const float* bo  = (const float*)d_in[10];
  const float* g1  = (const float*)d_in[11];
  const float* be1 = (const float*)d_in[12];
  const float* W1  = (const float*)d_in[13];
  const float* bf1 = (const float*)d_in[14];
  const float* W2  = (const float*)d_in[15];
  const float* bf2 = (const float*)d_in[16];
  const float* g2  = (const float*)d_in[17];
  const float* be2 = (const float*)d_in[18];

  unsigned short* xb    = (unsigned short*)d_ws;        // 8192*512 (f16)
  unsigned short* wqkvt = xb + 4194304;                 // 1536*512 (f16, B^T)
  unsigned short* wot   = wqkvt + 786432;               // 512*512 (bf16)
  unsigned short* w1t   = wot + 262144;                 // 768*512 (bf16)
  unsigned short* w2t   = w1t + 393216;                 // 512*768 (bf16)
  unsigned short* qkv   = w2t + 393216;                 // 8192*1536 (f16)
  unsigned short* oproj = qkv + 12582912;               // 8192*512 (bf16)
  unsigned short* y     = oproj + 4194304;              // 8192*512 (bf16)
  unsigned short* att   = xb;                           // bf16 (xb dead after G1)
  unsigned short* h     = qkv;                          // bf16 (qkv dead after attn)
  unsigned short* f     = oproj;                        // bf16 (oproj dead after LN1)

  k_cvt<1><<<2048, 256, 0, stream>>>(x, xb, 8192 * 512 / 8);
  k_tpose_all<<<1792, dim3(32, 8), 0, stream>>>(Wq, Wk, Wv, Wo, W1, W2,
                                                wqkvt, wot, w1t, w2t);

  // G1: qkv = x @ [Wq|Wk|Wv] + [bq|bk|bv]   (fp16), 24x64 = 1536 blocks
  k_gemm<0, 1, 1><<<dim3(24, 64), 256, 0, stream>>>(xb, wqkvt, bq, bk, bv, qkv, 8192, 1536, 512);
  // attention (pre-Wo output, bf16)
  k_attn<<<2048, 256, 0, stream>>>(qkv, adj, inx, att);
  // G2: oproj = relu(att @ Wo + bo), 8x64 = 512 blocks
  k_gemm<1, 0, 0><<<dim3(8, 64), 256, 0, stream>>>(att, wot, bo, bo, bo, oproj, 8192, 512, 512);
  // y = LN(x + oproj)
  k_ln1<<<2048, 256, 0, stream>>>(x, oproj, g1, be1, y);
  // G3: h = relu(y @ W1 + bf1), 12x64 = 768 blocks
  k_gemm<1, 0, 0><<<dim3(12, 64), 256, 0, stream>>>(y, w1t, bf1, bf1, bf1, h, 8192, 768, 512);
  // G4: f = h @ W2 + bf2, 8x64 = 512 blocks
  k_gemm<0, 0, 0><<<dim3(8, 64), 256, 0, stream>>>(h, w2t, bf2, bf2, bf2, f, 8192, 512, 768);
  // out = LN(y + f)
  k_ln2<<<2048, 256, 0, stream>>>(y, f, g2, be2, (float*)d_out);
}

// Round 7
// 115.924 us; speedup vs baseline: 1.6218x; 1.0917x over previous
//
#include <hip/hip_runtime.h>
#include <stdint.h>

typedef __attribute__((ext_vector_type(8))) short short8;
typedef __attribute__((ext_vector_type(4))) float f32x4;
typedef __attribute__((ext_vector_type(2))) _Float16 h2;
typedef __attribute__((ext_vector_type(8))) _Float16 half8;

static __device__ __forceinline__ unsigned short f2bf(float f) {
  unsigned int u = __float_as_uint(f);
  u += 0x7FFFu + ((u >> 16) & 1u);
  return (unsigned short)(u >> 16);
}
static __device__ __forceinline__ float bf2f(unsigned short h) {
  return __uint_as_float(((unsigned int)h) << 16);
}
static __device__ __forceinline__ unsigned short f2h(float f) {
  _Float16 h = (_Float16)f;
  return __builtin_bit_cast(unsigned short, h);
}
static __device__ __forceinline__ float hdot2(unsigned int a, unsigned int b, float c) {
  return __builtin_amdgcn_fdot2(__builtin_bit_cast(h2, a), __builtin_bit_cast(h2, b), c, false);
}

#define GLD16(gp, lp) __builtin_amdgcn_global_load_lds( \
    (__attribute__((address_space(1))) void*)(gp), \
    (__attribute__((address_space(3))) void*)(lp), 16, 0, 0)

// ---------------- fp32 -> f16 rows, batch->XCD-pair affinity --------------
// 2048 blocks, 4 rows each; block bid serves batch (bid&7)>>1.
__global__ __launch_bounds__(256) void k_cvt(const float* __restrict__ in,
                                             unsigned short* __restrict__ out) {
  const int bid = blockIdx.x;
  const int xcd = bid & 7;
  const int bb = xcd >> 1;
  const int s = ((bid >> 3) << 1) | (xcd & 1);        // 0..511
  const long row = ((long)bb << 11) | ((long)s << 2) | (threadIdx.x >> 6);
  const int lane = threadIdx.x & 63;
  const float4* p = (const float4*)(in + row * 512 + lane * 8);
  float4 a = p[0], b = p[1];
  short8 v;
  v[0] = (short)f2h(a.x); v[1] = (short)f2h(a.y);
  v[2] = (short)f2h(a.z); v[3] = (short)f2h(a.w);
  v[4] = (short)f2h(b.x); v[5] = (short)f2h(b.y);
  v[6] = (short)f2h(b.z); v[7] = (short)f2h(b.w);
  *(short8*)(out + row * 512 + lane * 8) = v;
}

// -------- adj mask pre-gather: maskb[row][kk] = adj>0 ? 0 : -1e22 ---------
// 1024 blocks x 256 threads, 8 rows/block, one lane per (row,kk).
__global__ __launch_bounds__(256) void k_mask(const float* __restrict__ adj,
                                              const int* __restrict__ inxs,
                                              float* __restrict__ maskb) {
  const int bid = blockIdx.x;
  const int xcd = bid & 7;
  const int bb = xcd >> 1;
  const int s = ((bid >> 3) << 1) | (xcd & 1);        // 0..255
  const long row = ((long)bb << 11) | ((long)s << 3) | (threadIdx.x >> 5);
  const int kk = threadIdx.x & 31;
  const int idx = inxs[row * 32 + kk];
  const float a = adj[row * 2048 + idx];
  maskb[row * 32 + kk] = a > 0.f ? 0.f : -1e22f;
}

// ------------- ALL weight transposes in one launch (1792 tiles) -----------
__global__ __launch_bounds__(256) void k_tpose_all(
    const float* __restrict__ Wq, const float* __restrict__ Wk,
    const float* __restrict__ Wv, const float* __restrict__ Wo,
    const float* __restrict__ W1, const float* __restrict__ W2,
    unsigned short* __restrict__ wqkvt, unsigned short* __restrict__ wot,
    unsigned short* __restrict__ w1t, unsigned short* __restrict__ w2t) {
  __shared__ float tile[32][33];
  const int bid = blockIdx.x;
  const float* src;
  unsigned short* dst;
  int R, C, f16, local;
  if (bid < 768) {
    const int m = bid >> 8;
    src = m == 0 ? Wq : (m == 1 ? Wk : Wv);
    dst = wqkvt + (long)m * 512 * 512;
    R = 512; C = 512; f16 = 1; local = bid & 255;
  } else if (bid < 1024) {
    src = Wo; dst = wot; R = 512; C = 512; f16 = 0; local = bid - 768;
  } else if (bid < 1408) {
    src = W1; dst = w1t; R = 512; C = 768; f16 = 0; local = bid - 1024;
  } else {
    src = W2; dst = w2t; R = 768; C = 512; f16 = 0; local = bid - 1408;
  }
  const int ntx = C >> 5;
  const int c0 = (local % ntx) << 5;
  const int r0 = (local / ntx) << 5;
  const int tx = threadIdx.x, ty = threadIdx.y;
#pragma unroll
  for (int i = 0; i < 4; i++)
    tile[ty + i * 8][tx] = src[(long)(r0 + ty + i * 8) * C + c0 + tx];
  __syncthreads();
#pragma unroll
  for (int i = 0; i < 4; i++) {
    float v = tile[tx][ty + i * 8];
    dst[(long)(c0 + ty + i * 8) * R + r0 + tx] = f16 ? f2h(v) : f2bf(v);
  }
}

// ------- 16-bit MFMA GEMM, 128x64 tile, BK=64, dbuf + counted vmcnt -------
// 1-D grid of (M/128)*(N/64) blocks; batch->XCD-pair affinity swizzle so
// rows of batch b are produced/consumed on XCDs {2b,2b+1} (M=8192 fixed).
template <int EPI, int F16, int QKVB>
__global__ __launch_bounds__(256) void k_gemm(const unsigned short* __restrict__ A,
                                              const unsigned short* __restrict__ Bt,
                                              const float* __restrict__ bias,
                                              const float* __restrict__ bias2,
                                              const float* __restrict__ bias3,
                                              unsigned short* __restrict__ C,
                                              int M, int N, int K) {
  __shared__ unsigned short As[2][128 * 64];
  __shared__ unsigned short Bs[2][64 * 64];
  const int t = threadIdx.x;
  const int lane = t & 63;
  const int w = t >> 6;
  const int wr = w >> 1, wc = w & 1;
  const int lin = blockIdx.x;
  const int xcd = lin & 7;
  const int bb = xcd >> 1;
  const int nx = N >> 6;
  const int s = ((lin >> 3) << 1) | (xcd & 1);  // 0..16*nx-1
  const int m0 = (bb * 16 + s / nx) * 128;
  const int n0 = (s % nx) * 64;

  f32x4 acc[4][2];
#pragma unroll
  for (int mi = 0; mi < 4; mi++)
#pragma unroll
    for (int ni = 0; ni < 2; ni++) {
      f32x4 z = {0.f, 0.f, 0.f, 0.f};
      acc[mi][ni] = z;
    }

  auto stage = [&](int buf, int k0) {
#pragma unroll
    for (int i = 0; i < 4; i++) {
      const int c = t + i * 256;
      const int r = c >> 3, j = c & 7;
      GLD16(A + (long)(m0 + r) * K + k0 + ((j ^ (r & 7)) << 3), &As[buf][c * 8]);
    }
#pragma unroll
    for (int i = 0; i < 2; i++) {
      const int c = t + i * 256;
      const int r = c >> 3, j = c & 7;
      GLD16(Bt + (long)(n0 + r) * K + k0 + ((j ^ (r & 7)) << 3), &Bs[buf][c * 8]);
    }
  };

  const int nt = K >> 6;
  stage(0, 0);
  for (int tt = 0; tt < nt; ++tt) {
    const int cur = tt & 1;
    if (tt + 1 < nt) {
      stage(cur ^ 1, (tt + 1) << 6);
      asm volatile("s_waitcnt vmcnt(6)" ::: "memory");
    } else {
      asm volatile("s_waitcnt vmcnt(0)" ::: "memory");
    }
    __builtin_amdgcn_s_barrier();

#pragma unroll
    for (int kk = 0; kk < 2; kk++) {
      short8 af[4], bf[2];
#pragma unroll
      for (int mi = 0; mi < 4; mi++) {
        const int r = wr * 64 + mi * 16 + (lane & 15);
        const int jj = (kk << 2) + (lane >> 4);
        af[mi] = *(const short8*)&As[cur][r * 64 + ((jj ^ (r & 7)) << 3)];
      }
#pragma unroll
      for (int ni = 0; ni < 2; ni++) {
        const int r = wc * 32 + ni * 16 + (lane & 15);
        const int jj = (kk << 2) + (lane >> 4);
        bf[ni] = *(const short8*)&Bs[cur][r * 64 + ((jj ^ (r & 7)) << 3)];
      }
#pragma unroll
      for (int mi = 0; mi < 4; mi++)
#pragma unroll
        for (int ni = 0; ni < 2; ni++) {
          if (F16)
            acc[mi][ni] = __builtin_amdgcn_mfma_f32_16x16x32_f16(
                __builtin_bit_cast(half8, af[mi]), __builtin_bit_cast(half8, bf[ni]),
                acc[mi][ni], 0, 0, 0);
          else
            acc[mi][ni] = __builtin_amdgcn_mfma_f32_16x16x32_bf16(af[mi], bf[ni], acc[mi][ni], 0, 0, 0);
        }
    }
    asm volatile("s_waitcnt lgkmcnt(0)" ::: "memory");
    __builtin_amdgcn_s_barrier();
  }

  const int lr = (lane >> 4) * 4;
  const int lc = lane & 15;
#pragma unroll
  for (int mi = 0; mi < 4; mi++) {
#pragma unroll
    for (int ni = 0; ni < 2; ni++) {
      const int col = n0 + wc * 32 + ni * 16 + lc;
      float bv;
      if (QKVB)
        bv = col < 512 ? bias[col] : (col < 1024 ? bias2[col - 512] : bias3[col - 1024]);
      else
        bv = bias[col];
#pragma unroll
      for (int r = 0; r < 4; r++) {
        const int row = m0 + wr * 64 + mi * 16 + lr + r;
        float v = acc[mi][ni][r] + bv;
        if (EPI == 1) v = fmaxf(v, 0.f);
        C[(long)row * N + col] = F16 ? f2h(v) : f2bf(v);
      }
    }
  }
}

// ---------------- attention: ONE WAVE per row, no barriers, no LDS --------
// k/v gathers hit the batch's XCD-pair L2 (written there by G1's swizzle).
// adj mask comes precomputed from maskb (coalesced 4B/lane).
__global__ __launch_bounds__(256) void k_attn(const unsigned short* __restrict__ qkv,
                                              const float* __restrict__ maskb,
                                              const int* __restrict__ inxs,
                                              unsigned short* __restrict__ att) {
  const int t = threadIdx.x;
  const int lane = t & 63;
  const int w = t >> 6;
  const int bid = blockIdx.x;
  const int xcd = bid & 7;
  const int b = xcd >> 1;
  const int sub = ((bid >> 3) << 1) | (xcd & 1);
  const int row = (b << 11) | (sub << 2) | w;
  const long base = (long)b * 2048;
  const int g = lane >> 4;
  const int li = lane & 15;
  const int kk = lane & 31;

  const int* ix = inxs + (long)row * 32;
  const int ixv = ix[kk];
  const float mval = maskb[(long)row * 32 + kk];

  const uint4* qp = (const uint4*)(qkv + (long)row * 1536);
  uint4 qc[4];
#pragma unroll
  for (int c = 0; c < 4; c++) qc[c] = qp[li + c * 16];

  // scores: 8 rounds x 4 neighbors, 1-round-ahead k prefetch
  float scr[8];
  uint4 ka[4], kb[4];
  {
    const int nb = __shfl(ixv, g, 64);
    const uint4* kp = (const uint4*)(qkv + (base + nb) * 1536 + 512);
#pragma unroll
    for (int c = 0; c < 4; c++) ka[c] = kp[li + c * 16];
  }
#pragma unroll
  for (int r = 0; r < 8; r++) {
    uint4* curk = (r & 1) ? kb : ka;
    uint4* nxtk = (r & 1) ? ka : kb;
    if (r < 7) {
      const int nb = __shfl(ixv, (r + 1) * 4 + g, 64);
      const uint4* kp = (const uint4*)(qkv + (base + nb) * 1536 + 512);
#pragma unroll
      for (int c = 0; c < 4; c++) nxtk[c] = kp[li + c * 16];
    }
    float d = 0.f;
#pragma unroll
    for (int c = 0; c < 4; c++) {
      d = hdot2(curk[c].x, qc[c].x, d);
      d = hdot2(curk[c].y, qc[c].y, d);
      d = hdot2(curk[c].z, qc[c].z, d);
      d = hdot2(curk[c].w, qc[c].w, d);
    }
#pragma unroll
    for (int m = 1; m <= 8; m <<= 1) d += __shfl_xor(d, m, 64);
    scr[r] = d;
  }

  // redistribute: lane kk takes scr[kk>>2] from lane (kk&3)*16
  const int srcl = (kk & 3) << 4;
  float s = __shfl(scr[0], srcl, 64);
#pragma unroll
  for (int r = 1; r < 8; r++) {
    const float tr = __shfl(scr[r], srcl, 64);
    s = ((kk >> 2) == r) ? tr : s;
  }
  s = s * 0.044194173824159216f + mval;

  // softmax across 32 owned scores
  float mx = s;
#pragma unroll
  for (int d = 1; d <= 16; d <<= 1) mx = fmaxf(mx, __shfl_xor(mx, d, 64));
  const float e = __expf(s - mx);
  float ts = e;
#pragma unroll
  for (int d = 1; d <= 16; d <<= 1) ts += __shfl_xor(ts, d, 64);
  const float inv = 1.f / ts;

  // PV: 16 neighbor pairs, 1-pair-ahead prefetch
  float o[8] = {0, 0, 0, 0, 0, 0, 0, 0};
  uint4 va0, va1, vb0, vb1;
  {
    const int u0 = __shfl(ixv, 0, 64);
    const int u1 = __shfl(ixv, 1, 64);
    va0 = *(const uint4*)(qkv + (base + u0) * 1536 + 1024 + lane * 8);
    va1 = *(const uint4*)(qkv + (base + u1) * 1536 + 1024 + lane * 8);
  }
#pragma unroll
  for (int p = 0; p < 16; p++) {
    const uint4 v0c = (p & 1) ? vb0 : va0;
    const uint4 v1c = (p & 1) ? vb1 : va1;
    if (p < 15) {
      const int u0 = __shfl(ixv, 2 * p + 2, 64);
      const int u1 = __shfl(ixv, 2 * p + 3, 64);
      const uint4 n0 = *(const uint4*)(qkv + (base + u0) * 1536 + 1024 + lane * 8);
      const uint4 n1 = *(const uint4*)(qkv + (base + u1) * 1536 + 1024 + lane * 8);
      if (p & 1) { va0 = n0; va1 = n1; } else { vb0 = n0; vb1 = n1; }
    }
    const float pe0 = __shfl(e, 2 * p, 64);
    const float pe1 = __shfl(e, 2 * p + 1, 64);
    const unsigned int pp =
        __builtin_bit_cast(unsigned int, __builtin_amdgcn_cvt_pkrtz(pe0, pe1));
    const unsigned int vw0[4] = {v0c.x, v0c.y, v0c.z, v0c.w};
    const unsigned int vw1[4] = {v1c.x, v1c.y, v1c.z, v1c.w};
#pragma unroll
    for (int q = 0; q < 4; q++) {
      const unsigned int even = __builtin_amdgcn_perm(vw1[q], vw0[q], 0x05040100u);
      const unsigned int odd  = __builtin_amdgcn_perm(vw1[q], vw0[q], 0x07060302u);
      o[2 * q]     = hdot2(even, pp, o[2 * q]);
      o[2 * q + 1] = hdot2(odd,  pp, o[2 * q + 1]);
    }
  }

  short8 ov;
#pragma unroll
  for (int j = 0; j < 8; j++) ov[j] = (short)f2bf(o[j] * inv);
  *(short8*)(att + (long)row * 512 + lane * 8) = ov;
}

// ---------------- LN1: y = LN(x_f32 + o_bf16) * g + beta, out bf16 --------
__global__ __launch_bounds__(256) void k_ln1(const float* __restrict__ x,
                                             const unsigned short* __restrict__ o,
                                             const float* __restrict__ g,
                                             const float* __restrict__ beta,
                                             unsigned short* __restrict__ y) {
  const int lane = threadIdx.x & 63;
  const int w = threadIdx.x >> 6;
  const int bid = blockIdx.x;
  const int xcd = bid & 7;
  const int bb = xcd >> 1;
  const int s0 = ((bid >> 3) << 1) | (xcd & 1);
  const long row = ((long)bb << 11) | ((long)s0 << 2) | w;
  const float4* xp = (const float4*)(x + row * 512 + lane * 8);
  float4 x0 = xp[0], x1 = xp[1];
  short8 ov = *(const short8*)(o + row * 512 + lane * 8);
  float tv[8] = {x0.x, x0.y, x0.z, x0.w, x1.x, x1.y, x1.z, x1.w};
  float s = 0.f, s2 = 0.f;
#pragma unroll
  for (int j = 0; j < 8; j++) {
    tv[j] += bf2f((unsigned short)ov[j]);
    s += tv[j];
    s2 += tv[j] * tv[j];
  }
#pragma unroll
  for (int m = 32; m >= 1; m >>= 1) {
    s += __shfl_xor(s, m, 64);
    s2 += __shfl_xor(s2, m, 64);
  }
  const float mean = s * (1.f / 512.f);
  const float var = s2 * (1.f / 512.f) - mean * mean;
  const float r = rsqrtf(var + 1e-5f);
  const float4* gp = (const float4*)(g + lane * 8);
  const float4* bp = (const float4*)(beta + lane * 8);
  float4 g0 = gp[0], g1v = gp[1], b0 = bp[0], b1 = bp[1];
  float gg[8] = {g0.x, g0.y, g0.z, g0.w, g1v.x, g1v.y, g1v.z, g1v.w};
  float bb2[8] = {b0.x, b0.y, b0.z, b0.w, b1.x, b1.y, b1.z, b1.w};
  short8 yv;
#pragma unroll
  for (int j = 0; j < 8; j++) yv[j] = (short)f2bf((tv[j] - mean) * r * gg[j] + bb2[j]);
  *(short8*)(y + row * 512 + lane * 8) = yv;
}

// ---------------- LN2: out_f32 = LN(y_bf16 + f_bf16) * g + beta -----------
__global__ __launch_bounds__(256) void k_ln2(const unsigned short* __restrict__ y,
                                             const unsigned short* __restrict__ f,
                                             const float* __restrict__ g,
                                             const float* __restrict__ beta,
                                             float* __restrict__ out) {
  const int lane = threadIdx.x & 63;
  const int w = threadIdx.x >> 6;
  const int bid = blockIdx.x;
  const int xcd = bid & 7;
  const int bb = xcd >> 1;
  const int s0 = ((bid >> 3) << 1) | (xcd & 1);
  const long row = ((long)bb << 11) | ((long)s0 << 2) | w;
  short8 yv = *(const short8*)(y + row * 512 + lane * 8);
  short8 fv = *(const short8*)(f + row * 512 + lane * 8);
  float tv[8];
  float s = 0.f, s2 = 0.f;
#pragma unroll
  for (int j = 0; j < 8; j++) {
    tv[j] = bf2f((unsigned short)yv[j]) + bf2f((unsigned short)fv[j]);
    s += tv[j];
    s2 += tv[j] * tv[j];
  }
#pragma unroll
  for (int m = 32; m >= 1; m >>= 1) {
    s += __shfl_xor(s, m, 64);
    s2 += __shfl_xor(s2, m, 64);
  }
  const float mean = s * (1.f / 512.f);
  const float var = s2 * (1.f / 512.f) - mean * mean;
  const float r = rsqrtf(var + 1e-5f);
  const float4* gp = (const float4*)(g + lane * 8);
  const float4* bp = (const float4*)(beta + lane * 8);
  float4 g0 = gp[0], g1v = gp[1], b0 = bp[0], b1 = bp[1];
  float gg[8] = {g0.x, g0.y, g0.z, g0.w, g1v.x, g1v.y, g1v.z, g1v.w};
  float bb2[8] = {b0.x, b0.y, b0.z, b0.w, b1.x, b1.y, b1.z, b1.w};
  float ovv[8];
#pragma unroll
  for (int j = 0; j < 8; j++) ovv[j] = (tv[j] - mean) * r * gg[j] + bb2[j];
  float4* op = (float4*)(out + row * 512 + lane * 8);
  float4 o0 = {ovv[0], ovv[1], ovv[2], ovv[3]};
  float4 o1 = {ovv[4], ovv[5], ovv[6], ovv[7]};
  op[0] = o0;
  op[1] = o1;
}

extern "C" void kernel_launch(void* const* d_in, const int* in_sizes, int n_in,
                              void* d_out, int out_size, void* d_ws, size_t ws_size,
                              hipStream_t stream) {
  const float* x   = (const float*)d_in[0];
  const float* adj = (const float*)d_in[1];
  const int*   inx = (const int*)d_in[2];
  const float* Wq  = (const float*)d_in[3];
  const float* bq  = (const float*)d_in[4];
  const float* Wk  = (const float*)d_in[5];
  const float* bk  = (const float*)d_in[6];
  const float* Wv  = (const float*)d_in[7];
  const float* bv  = (const float*)d_in[8];
  const float* Wo  = (const float*)d_in[9];
  const float* bo  = (const float*)d_in[10];
  const float* g1  = (const float*)d_in[11];
  const float* be1 = (const float*)d_in[12];
  const float* W1  = (const float*)d_in[13];
  const float* bf1 = (const float*)d_in[14];
  const float* W2  = (const float*)d_in[15];
  const float* bf2 = (const float*)d_in[16];
  const float* g2  = (const float*)d_in[17];
  const float* be2 = (const float*)d_in[18];

  unsigned short* xb    = (unsigned short*)d_ws;        // 8192*512 (f16)
  unsigned short* wqkvt = xb + 4194304;                 // 1536*512 (f16, B^T)
  unsigned short* wot   = wqkvt + 786432;               // 512*512 (bf16)
  unsigned short* w1t   = wot + 262144;                 // 768*512 (bf16)
  unsigned short* w2t   = w1t + 393216;                 // 512*768 (bf16)
  unsigned short* qkv   = w2t + 393216;                 // 8192*1536 (f16)
  unsigned short* oproj = qkv + 12582912;               // 8192*512 (bf16)
  unsigned short* y     = oproj + 4194304;              // 8192*512 (bf16)
  float*          maskb = (float*)(y + 4194304);        // 8192*32 f32 (1 MB)
  unsigned short* att   = xb;                           // bf16 (xb dead after G1)
  unsigned short* h     = qkv;                          // bf16 (qkv dead after attn)
  unsigned short* f     = oproj;                        // bf16 (oproj dead after LN1)

  k_mask<<<1024, 256, 0, stream>>>(adj, inx, maskb);
  k_cvt<<<2048, 256, 0, stream>>>(x, xb);
  k_tpose_all<<<1792, dim3(32, 8), 0, stream>>>(Wq, Wk, Wv, Wo, W1, W2,
                                                wqkvt, wot, w1t, w2t);

  // G1: qkv = x @ [Wq|Wk|Wv] + [bq|bk|bv]   (fp16), 1536 blocks, affinity swz
  k_gemm<0, 1, 1><<<1536, 256, 0, stream>>>(xb, wqkvt, bq, bk, bv, qkv, 8192, 1536, 512);
  // attention (pre-Wo output, bf16)
  k_attn<<<2048, 256, 0, stream>>>(qkv, maskb, inx, att);
  // G2: oproj = relu(att @ Wo + bo), 512 blocks
  k_gemm<1, 0, 0><<<512, 256, 0, stream>>>(att, wot, bo, bo, bo, oproj, 8192, 512, 512);
  // y = LN(x + oproj)
  k_ln1<<<2048, 256, 0, stream>>>(x, oproj, g1, be1, y);
  // G3: h = relu(y @ W1 + bf1), 768 blocks
  k_gemm<1, 0, 0><<<768, 256, 0, stream>>>(y, w1t, bf1, bf1, bf1, h, 8192, 768, 512);
  // G4: f = h @ W2 + bf2, 512 blocks
  k_gemm<0, 0, 0><<<512, 256, 0, stream>>>(h, w2t, bf2, bf2, bf2, f, 8192, 512, 768);
  // out = LN(y + f)
  k_ln2<<<2048, 256, 0, stream>>>(y, f, g2, be2, (float*)d_out);
}

// Round 8
// 114.517 us; speedup vs baseline: 1.6417x; 1.0123x over previous
//
#include <hip/hip_runtime.h>
#include <stdint.h>

typedef __attribute__((ext_vector_type(8))) short short8;
typedef __attribute__((ext_vector_type(4))) float f32x4;
typedef __attribute__((ext_vector_type(2))) _Float16 h2;
typedef __attribute__((ext_vector_type(8))) _Float16 half8;

static __device__ __forceinline__ unsigned short f2bf(float f) {
  unsigned int u = __float_as_uint(f);
  u += 0x7FFFu + ((u >> 16) & 1u);
  return (unsigned short)(u >> 16);
}
static __device__ __forceinline__ float bf2f(unsigned short h) {
  return __uint_as_float(((unsigned int)h) << 16);
}
static __device__ __forceinline__ unsigned short f2h(float f) {
  _Float16 h = (_Float16)f;
  return __builtin_bit_cast(unsigned short, h);
}
static __device__ __forceinline__ float hdot2(unsigned int a, unsigned int b, float c) {
  return __builtin_amdgcn_fdot2(__builtin_bit_cast(h2, a), __builtin_bit_cast(h2, b), c, false);
}

#define GLD16(gp, lp) __builtin_amdgcn_global_load_lds( \
    (__attribute__((address_space(1))) void*)(gp), \
    (__attribute__((address_space(3))) void*)(lp), 16, 0, 0)

// --------- fused prep: adj-mask gather | x->f16 | all weight transposes ----
// grid = 1024 (mask) + 2048 (cvt) + 1792 (tpose) = 4864 blocks x 256.
__global__ __launch_bounds__(256) void k_prep(
    const float* __restrict__ adj, const int* __restrict__ inxs,
    float* __restrict__ maskb, const float* __restrict__ x,
    unsigned short* __restrict__ xb,
    const float* __restrict__ Wq, const float* __restrict__ Wk,
    const float* __restrict__ Wv, const float* __restrict__ Wo,
    const float* __restrict__ W1, const float* __restrict__ W2,
    unsigned short* __restrict__ wqkvt, unsigned short* __restrict__ wot,
    unsigned short* __restrict__ w1t, unsigned short* __restrict__ w2t) {
  __shared__ float tile[32][33];
  const int bid = blockIdx.x;
  const int t = threadIdx.x;
  if (bid < 1024) {
    // adj mask pre-gather: 8 rows/block, one lane per (row,kk), affinity swz
    const int xcd = bid & 7;
    const int bb = xcd >> 1;
    const int s = ((bid >> 3) << 1) | (xcd & 1);  // 0..255
    const long row = ((long)bb << 11) | ((long)s << 3) | (t >> 5);
    const int kk = t & 31;
    const int idx = inxs[row * 32 + kk];
    const float a = adj[row * 2048 + idx];
    maskb[row * 32 + kk] = a > 0.f ? 0.f : -1e22f;
    return;
  }
  if (bid < 3072) {
    // x -> f16, 4 rows/block, affinity swz
    const int lb = bid - 1024;
    const int xcd = lb & 7;
    const int bb = xcd >> 1;
    const int s = ((lb >> 3) << 1) | (xcd & 1);  // 0..511
    const long row = ((long)bb << 11) | ((long)s << 2) | (t >> 6);
    const int lane = t & 63;
    const float4* p = (const float4*)(x + row * 512 + lane * 8);
    float4 a = p[0], b = p[1];
    short8 v;
    v[0] = (short)f2h(a.x); v[1] = (short)f2h(a.y);
    v[2] = (short)f2h(a.z); v[3] = (short)f2h(a.w);
    v[4] = (short)f2h(b.x); v[5] = (short)f2h(b.y);
    v[6] = (short)f2h(b.z); v[7] = (short)f2h(b.w);
    *(short8*)(xb + row * 512 + lane * 8) = v;
    return;
  }
  // weight transposes: fp32 [R][C] -> f16/bf16 [C][R], 32x32 tiles
  const int lb = bid - 3072;
  const float* src;
  unsigned short* dst;
  int R, C, f16, local;
  if (lb < 768) {
    const int m = lb >> 8;
    src = m == 0 ? Wq : (m == 1 ? Wk : Wv);
    dst = wqkvt + (long)m * 512 * 512;
    R = 512; C = 512; f16 = 1; local = lb & 255;
  } else if (lb < 1024) {
    src = Wo; dst = wot; R = 512; C = 512; f16 = 0; local = lb - 768;
  } else if (lb < 1408) {
    src = W1; dst = w1t; R = 512; C = 768; f16 = 0; local = lb - 1024;
  } else {
    src = W2; dst = w2t; R = 768; C = 512; f16 = 0; local = lb - 1408;
  }
  const int ntx = C >> 5;
  const int c0 = (local % ntx) << 5;
  const int r0 = (local / ntx) << 5;
  const int tx = t & 31, ty = t >> 5;
#pragma unroll
  for (int i = 0; i < 4; i++)
    tile[ty + i * 8][tx] = src[(long)(r0 + ty + i * 8) * C + c0 + tx];
  __syncthreads();
#pragma unroll
  for (int i = 0; i < 4; i++) {
    float v = tile[tx][ty + i * 8];
    dst[(long)(c0 + ty + i * 8) * R + r0 + tx] = f16 ? f2h(v) : f2bf(v);
  }
}

// ------- 16-bit MFMA GEMM, 128x64 tile, BK=64, dbuf + counted vmcnt -------
// 1-D grid; batch->XCD-pair affinity swizzle (M=8192 fixed).
template <int EPI, int F16, int QKVB>
__global__ __launch_bounds__(256) void k_gemm(const unsigned short* __restrict__ A,
                                              const unsigned short* __restrict__ Bt,
                                              const float* __restrict__ bias,
                                              const float* __restrict__ bias2,
                                              const float* __restrict__ bias3,
                                              unsigned short* __restrict__ C,
                                              int M, int N, int K) {
  __shared__ unsigned short As[2][128 * 64];
  __shared__ unsigned short Bs[2][64 * 64];
  const int t = threadIdx.x;
  const int lane = t & 63;
  const int w = t >> 6;
  const int wr = w >> 1, wc = w & 1;
  const int lin = blockIdx.x;
  const int xcd = lin & 7;
  const int bb = xcd >> 1;
  const int nx = N >> 6;
  const int s = ((lin >> 3) << 1) | (xcd & 1);
  const int m0 = (bb * 16 + s / nx) * 128;
  const int n0 = (s % nx) * 64;

  f32x4 acc[4][2];
#pragma unroll
  for (int mi = 0; mi < 4; mi++)
#pragma unroll
    for (int ni = 0; ni < 2; ni++) {
      f32x4 z = {0.f, 0.f, 0.f, 0.f};
      acc[mi][ni] = z;
    }

  auto stage = [&](int buf, int k0) {
#pragma unroll
    for (int i = 0; i < 4; i++) {
      const int c = t + i * 256;
      const int r = c >> 3, j = c & 7;
      GLD16(A + (long)(m0 + r) * K + k0 + ((j ^ (r & 7)) << 3), &As[buf][c * 8]);
    }
#pragma unroll
    for (int i = 0; i < 2; i++) {
      const int c = t + i * 256;
      const int r = c >> 3, j = c & 7;
      GLD16(Bt + (long)(n0 + r) * K + k0 + ((j ^ (r & 7)) << 3), &Bs[buf][c * 8]);
    }
  };

  const int nt = K >> 6;
  stage(0, 0);
  for (int tt = 0; tt < nt; ++tt) {
    const int cur = tt & 1;
    if (tt + 1 < nt) {
      stage(cur ^ 1, (tt + 1) << 6);
      asm volatile("s_waitcnt vmcnt(6)" ::: "memory");
    } else {
      asm volatile("s_waitcnt vmcnt(0)" ::: "memory");
    }
    __builtin_amdgcn_s_barrier();

#pragma unroll
    for (int kk = 0; kk < 2; kk++) {
      short8 af[4], bf[2];
#pragma unroll
      for (int mi = 0; mi < 4; mi++) {
        const int r = wr * 64 + mi * 16 + (lane & 15);
        const int jj = (kk << 2) + (lane >> 4);
        af[mi] = *(const short8*)&As[cur][r * 64 + ((jj ^ (r & 7)) << 3)];
      }
#pragma unroll
      for (int ni = 0; ni < 2; ni++) {
        const int r = wc * 32 + ni * 16 + (lane & 15);
        const int jj = (kk << 2) + (lane >> 4);
        bf[ni] = *(const short8*)&Bs[cur][r * 64 + ((jj ^ (r & 7)) << 3)];
      }
#pragma unroll
      for (int mi = 0; mi < 4; mi++)
#pragma unroll
        for (int ni = 0; ni < 2; ni++) {
          if (F16)
            acc[mi][ni] = __builtin_amdgcn_mfma_f32_16x16x32_f16(
                __builtin_bit_cast(half8, af[mi]), __builtin_bit_cast(half8, bf[ni]),
                acc[mi][ni], 0, 0, 0);
          else
            acc[mi][ni] = __builtin_amdgcn_mfma_f32_16x16x32_bf16(af[mi], bf[ni], acc[mi][ni], 0, 0, 0);
        }
    }
    asm volatile("s_waitcnt lgkmcnt(0)" ::: "memory");
    __builtin_amdgcn_s_barrier();
  }

  const int lr = (lane >> 4) * 4;
  const int lc = lane & 15;
#pragma unroll
  for (int mi = 0; mi < 4; mi++) {
#pragma unroll
    for (int ni = 0; ni < 2; ni++) {
      const int col = n0 + wc * 32 + ni * 16 + lc;
      float bv;
      if (QKVB)
        bv = col < 512 ? bias[col] : (col < 1024 ? bias2[col - 512] : bias3[col - 1024]);
      else
        bv = bias[col];
#pragma unroll
      for (int r = 0; r < 4; r++) {
        const int row = m0 + wr * 64 + mi * 16 + lr + r;
        float v = acc[mi][ni][r] + bv;
        if (EPI == 1) v = fmaxf(v, 0.f);
        C[(long)row * N + col] = F16 ? f2h(v) : f2bf(v);
      }
    }
  }
}

// ---------------- attention: ONE WAVE per row, low-VGPR, no prefetch ------
// __launch_bounds__(256,8) pins the allocator to <=64 VGPR -> 8 waves/SIMD.
// k/v gathers hit the batch's XCD-pair L2 (written there by G1's swizzle);
// adj mask precomputed (maskb). TLP (not per-wave MLP) hides ~200cy L2 lat.
__global__ __launch_bounds__(256, 8) void k_attn(const unsigned short* __restrict__ qkv,
                                                 const float* __restrict__ maskb,
                                                 const int* __restrict__ inxs,
                                                 unsigned short* __restrict__ att) {
  const int t = threadIdx.x;
  const int lane = t & 63;
  const int w = t >> 6;
  const int bid = blockIdx.x;
  const int xcd = bid & 7;
  const int b = xcd >> 1;
  const int sub = ((bid >> 3) << 1) | (xcd & 1);
  const int row = (b << 11) | (sub << 2) | w;
  const long base = (long)b * 2048;
  const int g = lane >> 4;
  const int li = lane & 15;
  const int kk = lane & 31;

  const int* ix = inxs + (long)row * 32;
  const int ixv = ix[kk];
  const float mval = maskb[(long)row * 32 + kk];

  const uint4* qp = (const uint4*)(qkv + (long)row * 1536);
  uint4 qc[4];
#pragma unroll
  for (int c = 0; c < 4; c++) qc[c] = qp[li + c * 16];

  // scores: 8 rounds x 4 concurrent neighbors (16-lane group each)
  float scr[8];
#pragma unroll
  for (int r = 0; r < 8; r++) {
    const int nb = __shfl(ixv, r * 4 + g, 64);
    const uint4* kp = (const uint4*)(qkv + (base + nb) * 1536 + 512);
    float d = 0.f;
#pragma unroll
    for (int c = 0; c < 4; c++) {
      uint4 kc = kp[li + c * 16];
      d = hdot2(kc.x, qc[c].x, d);
      d = hdot2(kc.y, qc[c].y, d);
      d = hdot2(kc.z, qc[c].z, d);
      d = hdot2(kc.w, qc[c].w, d);
    }
#pragma unroll
    for (int m = 1; m <= 8; m <<= 1) d += __shfl_xor(d, m, 64);
    scr[r] = d;
  }

  // redistribute: lane kk takes scr[kk>>2] from lane (kk&3)*16
  const int srcl = (kk & 3) << 4;
  float s = __shfl(scr[0], srcl, 64);
#pragma unroll
  for (int r = 1; r < 8; r++) {
    const float tr = __shfl(scr[r], srcl, 64);
    s = ((kk >> 2) == r) ? tr : s;
  }
  s = s * 0.044194173824159216f + mval;

  // softmax across 32 owned scores
  float mx = s;
#pragma unroll
  for (int d = 1; d <= 16; d <<= 1) mx = fmaxf(mx, __shfl_xor(mx, d, 64));
  const float e = __expf(s - mx);
  float ts = e;
#pragma unroll
  for (int d = 1; d <= 16; d <<= 1) ts += __shfl_xor(ts, d, 64);
  const float inv = 1.f / ts;

  // PV: 16 neighbor pairs; each lane covers feats lane*8..lane*8+8
  float o[8] = {0, 0, 0, 0, 0, 0, 0, 0};
#pragma unroll
  for (int p = 0; p < 16; p++) {
    const int u0 = __shfl(ixv, 2 * p, 64);
    const int u1 = __shfl(ixv, 2 * p + 1, 64);
    const uint4 v0c = *(const uint4*)(qkv + (base + u0) * 1536 + 1024 + lane * 8);
    const uint4 v1c = *(const uint4*)(qkv + (base + u1) * 1536 + 1024 + lane * 8);
    const float pe0 = __shfl(e, 2 * p, 64);
    const float pe1 = __shfl(e, 2 * p + 1, 64);
    const unsigned int pp =
        __builtin_bit_cast(unsigned int, __builtin_amdgcn_cvt_pkrtz(pe0, pe1));
    const unsigned int vw0[4] = {v0c.x, v0c.y, v0c.z, v0c.w};
    const unsigned int vw1[4] = {v1c.x, v1c.y, v1c.z, v1c.w};
#pragma unroll
    for (int q = 0; q < 4; q++) {
      const unsigned int even = __builtin_amdgcn_perm(vw1[q], vw0[q], 0x05040100u);
      const unsigned int odd  = __builtin_amdgcn_perm(vw1[q], vw0[q], 0x07060302u);
      o[2 * q]     = hdot2(even, pp, o[2 * q]);
      o[2 * q + 1] = hdot2(odd,  pp, o[2 * q + 1]);
    }
  }

  short8 ov;
#pragma unroll
  for (int j = 0; j < 8; j++) ov[j] = (short)f2bf(o[j] * inv);
  *(short8*)(att + (long)row * 512 + lane * 8) = ov;
}

// ---------------- LN1: y = LN(x_f32 + o_bf16) * g + beta, out bf16 --------
__global__ __launch_bounds__(256) void k_ln1(const float* __restrict__ x,
                                             const unsigned short* __restrict__ o,
                                             const float* __restrict__ g,
                                             const float* __restrict__ beta,
                                             unsigned short* __restrict__ y) {
  const int lane = threadIdx.x & 63;
  const int w = threadIdx.x >> 6;
  const int bid = blockIdx.x;
  const int xcd = bid & 7;
  const int bb = xcd >> 1;
  const int s0 = ((bid >> 3) << 1) | (xcd & 1);
  const long row = ((long)bb << 11) | ((long)s0 << 2) | w;
  const float4* xp = (const float4*)(x + row * 512 + lane * 8);
  float4 x0 = xp[0], x1 = xp[1];
  short8 ov = *(const short8*)(o + row * 512 + lane * 8);
  float tv[8] = {x0.x, x0.y, x0.z, x0.w, x1.x, x1.y, x1.z, x1.w};
  float s = 0.f, s2 = 0.f;
#pragma unroll
  for (int j = 0; j < 8; j++) {
    tv[j] += bf2f((unsigned short)ov[j]);
    s += tv[j];
    s2 += tv[j] * tv[j];
  }
#pragma unroll
  for (int m = 32; m >= 1; m >>= 1) {
    s += __shfl_xor(s, m, 64);
    s2 += __shfl_xor(s2, m, 64);
  }
  const float mean = s * (1.f / 512.f);
  const float var = s2 * (1.f / 512.f) - mean * mean;
  const float r = rsqrtf(var + 1e-5f);
  const float4* gp = (const float4*)(g + lane * 8);
  const float4* bp = (const float4*)(beta + lane * 8);
  float4 g0 = gp[0], g1v = gp[1], b0 = bp[0], b1 = bp[1];
  float gg[8] = {g0.x, g0.y, g0.z, g0.w, g1v.x, g1v.y, g1v.z, g1v.w};
  float bb2[8] = {b0.x, b0.y, b0.z, b0.w, b1.x, b1.y, b1.z, b1.w};
  short8 yv;
#pragma unroll
  for (int j = 0; j < 8; j++) yv[j] = (short)f2bf((tv[j] - mean) * r * gg[j] + bb2[j]);
  *(short8*)(y + row * 512 + lane * 8) = yv;
}

// ---------------- LN2: out_f32 = LN(y_bf16 + f_bf16) * g + beta -----------
__global__ __launch_bounds__(256) void k_ln2(const unsigned short* __restrict__ y,
                                             const unsigned short* __restrict__ f,
                                             const float* __restrict__ g,
                                             const float* __restrict__ beta,
                                             float* __restrict__ out) {
  const int lane = threadIdx.x & 63;
  const int w = threadIdx.x >> 6;
  const int bid = blockIdx.x;
  const int xcd = bid & 7;
  const int bb = xcd >> 1;
  const int s0 = ((bid >> 3) << 1) | (xcd & 1);
  const long row = ((long)bb << 11) | ((long)s0 << 2) | w;
  short8 yv = *(const short8*)(y + row * 512 + lane * 8);
  short8 fv = *(const short8*)(f + row * 512 + lane * 8);
  float tv[8];
  float s = 0.f, s2 = 0.f;
#pragma unroll
  for (int j = 0; j < 8; j++) {
    tv[j] = bf2f((unsigned short)yv[j]) + bf2f((unsigned short)fv[j]);
    s += tv[j];
    s2 += tv[j] * tv[j];
  }
#pragma unroll
  for (int m = 32; m >= 1; m >>= 1) {
    s += __shfl_xor(s, m, 64);
    s2 += __shfl_xor(s2, m, 64);
  }
  const float mean = s * (1.f / 512.f);
  const float var = s2 * (1.f / 512.f) - mean * mean;
  const float r = rsqrtf(var + 1e-5f);
  const float4* gp = (const float4*)(g + lane * 8);
  const float4* bp = (const float4*)(beta + lane * 8);
  float4 g0 = gp[0], g1v = gp[1], b0 = bp[0], b1 = bp[1];
  float gg[8] = {g0.x, g0.y, g0.z, g0.w, g1v.x, g1v.y, g1v.z, g1v.w};
  float bb2[8] = {b0.x, b0.y, b0.z, b0.w, b1.x, b1.y, b1.z, b1.w};
  float ovv[8];
#pragma unroll
  for (int j = 0; j < 8; j++) ovv[j] = (tv[j] - mean) * r * gg[j] + bb2[j];
  float4* op = (float4*)(out + row * 512 + lane * 8);
  float4 o0 = {ovv[0], ovv[1], ovv[2], ovv[3]};
  float4 o1 = {ovv[4], ovv[5], ovv[6], ovv[7]};
  op[0] = o0;
  op[1] = o1;
}

extern "C" void kernel_launch(void* const* d_in, const int* in_sizes, int n_in,
                              void* d_out, int out_size, void* d_ws, size_t ws_size,
                              hipStream_t stream) {
  const float* x   = (const float*)d_in[0];
  const float* adj = (const float*)d_in[1];
  const int*   inx = (const int*)d_in[2];
  const float* Wq  = (const float*)d_in[3];
  const float* bq  = (const float*)d_in[4];
  const float* Wk  = (const float*)d_in[5];
  const float* bk  = (const float*)d_in[6];
  const float* Wv  = (const float*)d_in[7];
  const float* bv  = (const float*)d_in[8];
  const float* Wo  = (const float*)d_in[9];
  const float* bo  = (const float*)d_in[10];
  const float* g1  = (const float*)d_in[11];
  const float* be1 = (const float*)d_in[12];
  const float* W1  = (const float*)d_in[13];
  const float* bf1 = (const float*)d_in[14];
  const float* W2  = (const float*)d_in[15];
  const float* bf2 = (const float*)d_in[16];
  const float* g2  = (const float*)d_in[17];
  const float* be2 = (const float*)d_in[18];

  unsigned short* xb    = (unsigned short*)d_ws;        // 8192*512 (f16)
  unsigned short* wqkvt = xb + 4194304;                 // 1536*512 (f16, B^T)
  unsigned short* wot   = wqkvt + 786432;               // 512*512 (bf16)
  unsigned short* w1t   = wot + 262144;                 // 768*512 (bf16)
  unsigned short* w2t   = w1t + 393216;                 // 512*768 (bf16)
  unsigned short* qkv   = w2t + 393216;                 // 8192*1536 (f16)
  unsigned short* oproj = qkv + 12582912;               // 8192*512 (bf16)
  unsigned short* y     = oproj + 4194304;              // 8192*512 (bf16)
  float*          maskb = (float*)(y + 4194304);        // 8192*32 f32 (1 MB)
  unsigned short* att   = xb;                           // bf16 (xb dead after G1)
  unsigned short* h     = qkv;                          // bf16 (qkv dead after attn)
  unsigned short* f     = oproj;                        // bf16 (oproj dead after LN1)

  k_prep<<<4864, 256, 0, stream>>>(adj, inx, maskb, x, xb, Wq, Wk, Wv, Wo, W1, W2,
                                   wqkvt, wot, w1t, w2t);

  // G1: qkv = x @ [Wq|Wk|Wv] + [bq|bk|bv]   (fp16), 1536 blocks, affinity swz
  k_gemm<0, 1, 1><<<1536, 256, 0, stream>>>(xb, wqkvt, bq, bk, bv, qkv, 8192, 1536, 512);
  // attention (pre-Wo output, bf16)
  k_attn<<<2048, 256, 0, stream>>>(qkv, maskb, inx, att);
  // G2: oproj = relu(att @ Wo + bo), 512 blocks
  k_gemm<1, 0, 0><<<512, 256, 0, stream>>>(att, wot, bo, bo, bo, oproj, 8192, 512, 512);
  // y = LN(x + oproj)
  k_ln1<<<2048, 256, 0, stream>>>(x, oproj, g1, be1, y);
  // G3: h = relu(y @ W1 + bf1), 768 blocks
  k_gemm<1, 0, 0><<<768, 256, 0, stream>>>(y, w1t, bf1, bf1, bf1, h, 8192, 768, 512);
  // G4: f = h @ W2 + bf2, 512 blocks
  k_gemm<0, 0, 0><<<512, 256, 0, stream>>>(h, w2t, bf2, bf2, bf2, f, 8192, 512, 768);
  // out = LN(y + f)
  k_ln2<<<2048, 256, 0, stream>>>(y, f, g2, be2, (float*)d_out);
}

// Round 9
// 105.827 us; speedup vs baseline: 1.7765x; 1.0821x over previous
//
#include <hip/hip_runtime.h>
#include <stdint.h>

typedef __attribute__((ext_vector_type(8))) short short8;
typedef __attribute__((ext_vector_type(4))) float f32x4;
typedef __attribute__((ext_vector_type(2))) _Float16 h2;
typedef __attribute__((ext_vector_type(8))) _Float16 half8;

#define QSCALE 21.1666667f   /* 127/6 : quantize */
#define SCONST 9.86413e-5f   /* (6/127)^2 / sqrt(512) : score dequant */

static __device__ __forceinline__ unsigned short f2bf(float f) {
  unsigned int u = __float_as_uint(f);
  u += 0x7FFFu + ((u >> 16) & 1u);
  return (unsigned short)(u >> 16);
}
static __device__ __forceinline__ float bf2f(unsigned short h) {
  return __uint_as_float(((unsigned int)h) << 16);
}
static __device__ __forceinline__ unsigned short f2h(float f) {
  _Float16 h = (_Float16)f;
  return __builtin_bit_cast(unsigned short, h);
}
static __device__ __forceinline__ float hdot2(unsigned int a, unsigned int b, float c) {
  return __builtin_amdgcn_fdot2(__builtin_bit_cast(h2, a), __builtin_bit_cast(h2, b), c, false);
}
static __device__ __forceinline__ signed char q8(float v) {
  float sv = fminf(fmaxf(v * QSCALE, -127.f), 127.f);
  return (signed char)(int)rintf(sv);
}

#define GLD16(gp, lp) __builtin_amdgcn_global_load_lds( \
    (__attribute__((address_space(1))) void*)(gp), \
    (__attribute__((address_space(3))) void*)(lp), 16, 0, 0)

// --------- fused prep: adj-mask gather | x->f16 | all weight transposes ----
__global__ __launch_bounds__(256) void k_prep(
    const float* __restrict__ adj, const int* __restrict__ inxs,
    float* __restrict__ maskb, const float* __restrict__ x,
    unsigned short* __restrict__ xb,
    const float* __restrict__ Wq, const float* __restrict__ Wk,
    const float* __restrict__ Wv, const float* __restrict__ Wo,
    const float* __restrict__ W1, const float* __restrict__ W2,
    unsigned short* __restrict__ wqkvt, unsigned short* __restrict__ wot,
    unsigned short* __restrict__ w1t, unsigned short* __restrict__ w2t) {
  __shared__ float tile[32][33];
  const int bid = blockIdx.x;
  const int t = threadIdx.x;
  if (bid < 1024) {
    const int xcd = bid & 7;
    const int bb = xcd >> 1;
    const int s = ((bid >> 3) << 1) | (xcd & 1);
    const long row = ((long)bb << 11) | ((long)s << 3) | (t >> 5);
    const int kk = t & 31;
    const int idx = inxs[row * 32 + kk];
    const float a = adj[row * 2048 + idx];
    maskb[row * 32 + kk] = a > 0.f ? 0.f : -1e22f;
    return;
  }
  if (bid < 3072) {
    const int lb = bid - 1024;
    const int xcd = lb & 7;
    const int bb = xcd >> 1;
    const int s = ((lb >> 3) << 1) | (xcd & 1);
    const long row = ((long)bb << 11) | ((long)s << 2) | (t >> 6);
    const int lane = t & 63;
    const float4* p = (const float4*)(x + row * 512 + lane * 8);
    float4 a = p[0], b = p[1];
    short8 v;
    v[0] = (short)f2h(a.x); v[1] = (short)f2h(a.y);
    v[2] = (short)f2h(a.z); v[3] = (short)f2h(a.w);
    v[4] = (short)f2h(b.x); v[5] = (short)f2h(b.y);
    v[6] = (short)f2h(b.z); v[7] = (short)f2h(b.w);
    *(short8*)(xb + row * 512 + lane * 8) = v;
    return;
  }
  const int lb = bid - 3072;
  const float* src;
  unsigned short* dst;
  int R, C, f16, local;
  if (lb < 768) {
    const int m = lb >> 8;
    src = m == 0 ? Wq : (m == 1 ? Wk : Wv);
    dst = wqkvt + (long)m * 512 * 512;
    R = 512; C = 512; f16 = 1; local = lb & 255;
  } else if (lb < 1024) {
    src = Wo; dst = wot; R = 512; C = 512; f16 = 0; local = lb - 768;
  } else if (lb < 1408) {
    src = W1; dst = w1t; R = 512; C = 768; f16 = 0; local = lb - 1024;
  } else {
    src = W2; dst = w2t; R = 768; C = 512; f16 = 0; local = lb - 1408;
  }
  const int ntx = C >> 5;
  const int c0 = (local % ntx) << 5;
  const int r0 = (local / ntx) << 5;
  const int tx = t & 31, ty = t >> 5;
#pragma unroll
  for (int i = 0; i < 4; i++)
    tile[ty + i * 8][tx] = src[(long)(r0 + ty + i * 8) * C + c0 + tx];
  __syncthreads();
#pragma unroll
  for (int i = 0; i < 4; i++) {
    float v = tile[tx][ty + i * 8];
    dst[(long)(c0 + ty + i * 8) * R + r0 + tx] = f16 ? f2h(v) : f2bf(v);
  }
}

// ---- G1: f16 MFMA GEMM 128x128, BK=64, dbuf, epilogue -> int8 q,k | f16 v --
// A[8192][512] f16, Bt[1536][512] f16. Out: qk8 bytes [8192][1024], vh f16
// [8192][512]. 768 blocks, batch->XCD-pair affinity.
__global__ __launch_bounds__(256) void k_gemm_qkv(
    const unsigned short* __restrict__ A, const unsigned short* __restrict__ Bt,
    const float* __restrict__ bq, const float* __restrict__ bk,
    const float* __restrict__ bv, signed char* __restrict__ qk8,
    unsigned short* __restrict__ vh) {
  const int K = 512;
  __shared__ unsigned short As[2][128 * 64];
  __shared__ unsigned short Bs[2][128 * 64];
  const int t = threadIdx.x;
  const int lane = t & 63;
  const int w = t >> 6;
  const int wr = w >> 1, wc = w & 1;
  const int lin = blockIdx.x;
  const int xcd = lin & 7;
  const int bb = xcd >> 1;
  const int s = ((lin >> 3) << 1) | (xcd & 1);  // 0..191
  const int m0 = (bb * 16 + s / 12) * 128;
  const int n0 = (s % 12) * 128;

  f32x4 acc[4][4];
#pragma unroll
  for (int mi = 0; mi < 4; mi++)
#pragma unroll
    for (int ni = 0; ni < 4; ni++) {
      f32x4 z = {0.f, 0.f, 0.f, 0.f};
      acc[mi][ni] = z;
    }

  auto stage = [&](int buf, int k0) {
#pragma unroll
    for (int i = 0; i < 4; i++) {
      const int c = t + i * 256;
      const int r = c >> 3, j = c & 7;
      GLD16(A + (long)(m0 + r) * K + k0 + ((j ^ (r & 7)) << 3), &As[buf][c * 8]);
    }
#pragma unroll
    for (int i = 0; i < 4; i++) {
      const int c = t + i * 256;
      const int r = c >> 3, j = c & 7;
      GLD16(Bt + (long)(n0 + r) * K + k0 + ((j ^ (r & 7)) << 3), &Bs[buf][c * 8]);
    }
  };

  const int nt = K >> 6;  // 8
  stage(0, 0);
  for (int tt = 0; tt < nt; ++tt) {
    const int cur = tt & 1;
    if (tt + 1 < nt) {
      stage(cur ^ 1, (tt + 1) << 6);
      asm volatile("s_waitcnt vmcnt(8)" ::: "memory");
    } else {
      asm volatile("s_waitcnt vmcnt(0)" ::: "memory");
    }
    __builtin_amdgcn_s_barrier();

#pragma unroll
    for (int kk = 0; kk < 2; kk++) {
      short8 af[4], bf[4];
#pragma unroll
      for (int mi = 0; mi < 4; mi++) {
        const int r = wr * 64 + mi * 16 + (lane & 15);
        const int jj = (kk << 2) + (lane >> 4);
        af[mi] = *(const short8*)&As[cur][r * 64 + ((jj ^ (r & 7)) << 3)];
      }
#pragma unroll
      for (int ni = 0; ni < 4; ni++) {
        const int r = wc * 64 + ni * 16 + (lane & 15);
        const int jj = (kk << 2) + (lane >> 4);
        bf[ni] = *(const short8*)&Bs[cur][r * 64 + ((jj ^ (r & 7)) << 3)];
      }
#pragma unroll
      for (int mi = 0; mi < 4; mi++)
#pragma unroll
        for (int ni = 0; ni < 4; ni++)
          acc[mi][ni] = __builtin_amdgcn_mfma_f32_16x16x32_f16(
              __builtin_bit_cast(half8, af[mi]), __builtin_bit_cast(half8, bf[ni]),
              acc[mi][ni], 0, 0, 0);
    }
    asm volatile("s_waitcnt lgkmcnt(0)" ::: "memory");
    __builtin_amdgcn_s_barrier();
  }

  const int lr = (lane >> 4) * 4;
  const int lc = lane & 15;
  if (n0 < 1024) {  // q or k columns -> int8
#pragma unroll
    for (int mi = 0; mi < 4; mi++) {
#pragma unroll
      for (int ni = 0; ni < 4; ni++) {
        const int col = n0 + wc * 64 + ni * 16 + lc;
        const float bvv = col < 512 ? bq[col] : bk[col - 512];
#pragma unroll
        for (int r = 0; r < 4; r++) {
          const int row = m0 + wr * 64 + mi * 16 + lr + r;
          qk8[(long)row * 1024 + col] = q8(acc[mi][ni][r] + bvv);
        }
      }
    }
  } else {  // v columns -> f16
#pragma unroll
    for (int mi = 0; mi < 4; mi++) {
#pragma unroll
      for (int ni = 0; ni < 4; ni++) {
        const int col = n0 + wc * 64 + ni * 16 + lc;
        const float bvv = bv[col - 1024];
#pragma unroll
        for (int r = 0; r < 4; r++) {
          const int row = m0 + wr * 64 + mi * 16 + lr + r;
          vh[(long)row * 512 + (col - 1024)] = f2h(acc[mi][ni][r] + bvv);
        }
      }
    }
  }
}

// ------- bf16 MFMA GEMM, 128x64 tile, BK=64, dbuf + counted vmcnt ---------
template <int EPI>
__global__ __launch_bounds__(256) void k_gemm(const unsigned short* __restrict__ A,
                                              const unsigned short* __restrict__ Bt,
                                              const float* __restrict__ bias,
                                              unsigned short* __restrict__ C,
                                              int M, int N, int K) {
  __shared__ unsigned short As[2][128 * 64];
  __shared__ unsigned short Bs[2][64 * 64];
  const int t = threadIdx.x;
  const int lane = t & 63;
  const int w = t >> 6;
  const int wr = w >> 1, wc = w & 1;
  const int lin = blockIdx.x;
  const int xcd = lin & 7;
  const int bb = xcd >> 1;
  const int nx = N >> 6;
  const int s = ((lin >> 3) << 1) | (xcd & 1);
  const int m0 = (bb * 16 + s / nx) * 128;
  const int n0 = (s % nx) * 64;

  f32x4 acc[4][2];
#pragma unroll
  for (int mi = 0; mi < 4; mi++)
#pragma unroll
    for (int ni = 0; ni < 2; ni++) {
      f32x4 z = {0.f, 0.f, 0.f, 0.f};
      acc[mi][ni] = z;
    }

  auto stage = [&](int buf, int k0) {
#pragma unroll
    for (int i = 0; i < 4; i++) {
      const int c = t + i * 256;
      const int r = c >> 3, j = c & 7;
      GLD16(A + (long)(m0 + r) * K + k0 + ((j ^ (r & 7)) << 3), &As[buf][c * 8]);
    }
#pragma unroll
    for (int i = 0; i < 2; i++) {
      const int c = t + i * 256;
      const int r = c >> 3, j = c & 7;
      GLD16(Bt + (long)(n0 + r) * K + k0 + ((j ^ (r & 7)) << 3), &Bs[buf][c * 8]);
    }
  };

  const int nt = K >> 6;
  stage(0, 0);
  for (int tt = 0; tt < nt; ++tt) {
    const int cur = tt & 1;
    if (tt + 1 < nt) {
      stage(cur ^ 1, (tt + 1) << 6);
      asm volatile("s_waitcnt vmcnt(6)" ::: "memory");
    } else {
      asm volatile("s_waitcnt vmcnt(0)" ::: "memory");
    }
    __builtin_amdgcn_s_barrier();

#pragma unroll
    for (int kk = 0; kk < 2; kk++) {
      short8 af[4], bf[2];
#pragma unroll
      for (int mi = 0; mi < 4; mi++) {
        const int r = wr * 64 + mi * 16 + (lane & 15);
        const int jj = (kk << 2) + (lane >> 4);
        af[mi] = *(const short8*)&As[cur][r * 64 + ((jj ^ (r & 7)) << 3)];
      }
#pragma unroll
      for (int ni = 0; ni < 2; ni++) {
        const int r = wc * 32 + ni * 16 + (lane & 15);
        const int jj = (kk << 2) + (lane >> 4);
        bf[ni] = *(const short8*)&Bs[cur][r * 64 + ((jj ^ (r & 7)) << 3)];
      }
#pragma unroll
      for (int mi = 0; mi < 4; mi++)
#pragma unroll
        for (int ni = 0; ni < 2; ni++)
          acc[mi][ni] = __builtin_amdgcn_mfma_f32_16x16x32_bf16(af[mi], bf[ni], acc[mi][ni], 0, 0, 0);
    }
    asm volatile("s_waitcnt lgkmcnt(0)" ::: "memory");
    __builtin_amdgcn_s_barrier();
  }

  const int lr = (lane >> 4) * 4;
  const int lc = lane & 15;
#pragma unroll
  for (int mi = 0; mi < 4; mi++) {
#pragma unroll
    for (int ni = 0; ni < 2; ni++) {
      const int col = n0 + wc * 32 + ni * 16 + lc;
      const float bvv = bias[col];
#pragma unroll
      for (int r = 0; r < 4; r++) {
        const int row = m0 + wr * 64 + mi * 16 + lr + r;
        float v = acc[mi][ni][r] + bvv;
        if (EPI == 1) v = fmaxf(v, 0.f);
        C[(long)row * N + col] = f2bf(v);
      }
    }
  }
}

// ---------------- attention: int8 q,k scores (sdot4), f16 v PV -------------
__global__ __launch_bounds__(256, 8) void k_attn(const signed char* __restrict__ qk8,
                                                 const unsigned short* __restrict__ vh,
                                                 const float* __restrict__ maskb,
                                                 const int* __restrict__ inxs,
                                                 unsigned short* __restrict__ att) {
  const int t = threadIdx.x;
  const int lane = t & 63;
  const int w = t >> 6;
  const int bid = blockIdx.x;
  const int xcd = bid & 7;
  const int b = xcd >> 1;
  const int sub = ((bid >> 3) << 1) | (xcd & 1);
  const int row = (b << 11) | (sub << 2) | w;
  const long base = (long)b * 2048;
  const int g = lane >> 4;
  const int li = lane & 15;
  const int kk = lane & 31;

  const int* ix = inxs + (long)row * 32;
  const int ixv = ix[kk];
  const float mval = maskb[(long)row * 32 + kk];

  // q8 chunks: lane li covers uint2 chunks {li, li+16, li+32, li+48} (8B each)
  const uint2* qp = (const uint2*)(qk8 + (long)row * 1024);
  uint2 qc[4];
#pragma unroll
  for (int c = 0; c < 4; c++) qc[c] = qp[li + c * 16];

  // scores: 8 rounds x 4 concurrent neighbors, int8 dot via sdot4
  float scr[8];
#pragma unroll
  for (int r = 0; r < 8; r++) {
    const int nb = __shfl(ixv, r * 4 + g, 64);
    const uint2* kp = (const uint2*)(qk8 + (base + nb) * 1024 + 512);
    int di = 0;
#pragma unroll
    for (int c = 0; c < 4; c++) {
      uint2 kc = kp[li + c * 16];
      di = __builtin_amdgcn_sdot4((int)kc.x, (int)qc[c].x, di, false);
      di = __builtin_amdgcn_sdot4((int)kc.y, (int)qc[c].y, di, false);
    }
#pragma unroll
    for (int m = 1; m <= 8; m <<= 1) di += __shfl_xor(di, m, 64);
    scr[r] = (float)di;
  }

  // redistribute: lane kk takes scr[kk>>2] from lane (kk&3)*16
  const int srcl = (kk & 3) << 4;
  float s = __shfl(scr[0], srcl, 64);
#pragma unroll
  for (int r = 1; r < 8; r++) {
    const float tr = __shfl(scr[r], srcl, 64);
    s = ((kk >> 2) == r) ? tr : s;
  }
  s = s * SCONST + mval;

  // softmax across 32 owned scores
  float mx = s;
#pragma unroll
  for (int d = 1; d <= 16; d <<= 1) mx = fmaxf(mx, __shfl_xor(mx, d, 64));
  const float e = __expf(s - mx);
  float ts = e;
#pragma unroll
  for (int d = 1; d <= 16; d <<= 1) ts += __shfl_xor(ts, d, 64);
  const float inv = 1.f / ts;

  // PV: 16 neighbor pairs (f16 v rows); each lane covers feats lane*8..+8
  float o[8] = {0, 0, 0, 0, 0, 0, 0, 0};
#pragma unroll
  for (int p = 0; p < 16; p++) {
    const int u0 = __shfl(ixv, 2 * p, 64);
    const int u1 = __shfl(ixv, 2 * p + 1, 64);
    const uint4 v0c = *(const uint4*)(vh + (base + u0) * 512 + lane * 8);
    const uint4 v1c = *(const uint4*)(vh + (base + u1) * 512 + lane * 8);
    const float pe0 = __shfl(e, 2 * p, 64);
    const float pe1 = __shfl(e, 2 * p + 1, 64);
    const unsigned int pp =
        __builtin_bit_cast(unsigned int, __builtin_amdgcn_cvt_pkrtz(pe0, pe1));
    const unsigned int vw0[4] = {v0c.x, v0c.y, v0c.z, v0c.w};
    const unsigned int vw1[4] = {v1c.x, v1c.y, v1c.z, v1c.w};
#pragma unroll
    for (int q = 0; q < 4; q++) {
      const unsigned int even = __builtin_amdgcn_perm(vw1[q], vw0[q], 0x05040100u);
      const unsigned int odd  = __builtin_amdgcn_perm(vw1[q], vw0[q], 0x07060302u);
      o[2 * q]     = hdot2(even, pp, o[2 * q]);
      o[2 * q + 1] = hdot2(odd,  pp, o[2 * q + 1]);
    }
  }

  short8 ov;
#pragma unroll
  for (int j = 0; j < 8; j++) ov[j] = (short)f2bf(o[j] * inv);
  *(short8*)(att + (long)row * 512 + lane * 8) = ov;
}

// ---------------- LN1: y = LN(x_f32 + o_bf16) * g + beta, out bf16 --------
__global__ __launch_bounds__(256) void k_ln1(const float* __restrict__ x,
                                             const unsigned short* __restrict__ o,
                                             const float* __restrict__ g,
                                             const float* __restrict__ beta,
                                             unsigned short* __restrict__ y) {
  const int lane = threadIdx.x & 63;
  const int w = threadIdx.x >> 6;
  const int bid = blockIdx.x;
  const int xcd = bid & 7;
  const int bb = xcd >> 1;
  const int s0 = ((bid >> 3) << 1) | (xcd & 1);
  const long row = ((long)bb << 11) | ((long)s0 << 2) | w;
  const float4* xp = (const float4*)(x + row * 512 + lane * 8);
  float4 x0 = xp[0], x1 = xp[1];
  short8 ov = *(const short8*)(o + row * 512 + lane * 8);
  float tv[8] = {x0.x, x0.y, x0.z, x0.w, x1.x, x1.y, x1.z, x1.w};
  float s = 0.f, s2 = 0.f;
#pragma unroll
  for (int j = 0; j < 8; j++) {
    tv[j] += bf2f((unsigned short)ov[j]);
    s += tv[j];
    s2 += tv[j] * tv[j];
  }
#pragma unroll
  for (int m = 32; m >= 1; m >>= 1) {
    s += __shfl_xor(s, m, 64);
    s2 += __shfl_xor(s2, m, 64);
  }
  const float mean = s * (1.f / 512.f);
  const float var = s2 * (1.f / 512.f) - mean * mean;
  const float r = rsqrtf(var + 1e-5f);
  const float4* gp = (const float4*)(g + lane * 8);
  const float4* bp = (const float4*)(beta + lane * 8);
  float4 g0 = gp[0], g1v = gp[1], b0 = bp[0], b1 = bp[1];
  float gg[8] = {g0.x, g0.y, g0.z, g0.w, g1v.x, g1v.y, g1v.z, g1v.w};
  float bb2[8] = {b0.x, b0.y, b0.z, b0.w, b1.x, b1.y, b1.z, b1.w};
  short8 yv;
#pragma unroll
  for (int j = 0; j < 8; j++) yv[j] = (short)f2bf((tv[j] - mean) * r * gg[j] + bb2[j]);
  *(short8*)(y + row * 512 + lane * 8) = yv;
}

// ---------------- LN2: out_f32 = LN(y_bf16 + f_bf16) * g + beta -----------
__global__ __launch_bounds__(256) void k_ln2(const unsigned short* __restrict__ y,
                                             const unsigned short* __restrict__ f,
                                             const float* __restrict__ g,
                                             const float* __restrict__ beta,
                                             float* __restrict__ out) {
  const int lane = threadIdx.x & 63;
  const int w = threadIdx.x >> 6;
  const int bid = blockIdx.x;
  const int xcd = bid & 7;
  const int bb = xcd >> 1;
  const int s0 = ((bid >> 3) << 1) | (xcd & 1);
  const long row = ((long)bb << 11) | ((long)s0 << 2) | w;
  short8 yv = *(const short8*)(y + row * 512 + lane * 8);
  short8 fv = *(const short8*)(f + row * 512 + lane * 8);
  float tv[8];
  float s = 0.f, s2 = 0.f;
#pragma unroll
  for (int j = 0; j < 8; j++) {
    tv[j] = bf2f((unsigned short)yv[j]) + bf2f((unsigned short)fv[j]);
    s += tv[j];
    s2 += tv[j] * tv[j];
  }
#pragma unroll
  for (int m = 32; m >= 1; m >>= 1) {
    s += __shfl_xor(s, m, 64);
    s2 += __shfl_xor(s2, m, 64);
  }
  const float mean = s * (1.f / 512.f);
  const float var = s2 * (1.f / 512.f) - mean * mean;
  const float r = rsqrtf(var + 1e-5f);
  const float4* gp = (const float4*)(g + lane * 8);
  const float4* bp = (const float4*)(beta + lane * 8);
  float4 g0 = gp[0], g1v = gp[1], b0 = bp[0], b1 = bp[1];
  float gg[8] = {g0.x, g0.y, g0.z, g0.w, g1v.x, g1v.y, g1v.z, g1v.w};
  float bb2[8] = {b0.x, b0.y, b0.z, b0.w, b1.x, b1.y, b1.z, b1.w};
  float ovv[8];
#pragma unroll
  for (int j = 0; j < 8; j++) ovv[j] = (tv[j] - mean) * r * gg[j] + bb2[j];
  float4* op = (float4*)(out + row * 512 + lane * 8);
  float4 o0 = {ovv[0], ovv[1], ovv[2], ovv[3]};
  float4 o1 = {ovv[4], ovv[5], ovv[6], ovv[7]};
  op[0] = o0;
  op[1] = o1;
}

extern "C" void kernel_launch(void* const* d_in, const int* in_sizes, int n_in,
                              void* d_out, int out_size, void* d_ws, size_t ws_size,
                              hipStream_t stream) {
  const float* x   = (const float*)d_in[0];
  const float* adj = (const float*)d_in[1];
  const int*   inx = (const int*)d_in[2];
  const float* Wq  = (const float*)d_in[3];
  const float* bq  = (const float*)d_in[4];
  const float* Wk  = (const float*)d_in[5];
  const float* bk  = (const float*)d_in[6];
  const float* Wv  = (const float*)d_in[7];
  const float* bv  = (const float*)d_in[8];
  const float* Wo  = (const float*)d_in[9];
  const float* bo  = (const float*)d_in[10];
  const float* g1  = (const float*)d_in[11];
  const float* be1 = (const float*)d_in[12];
  const float* W1  = (const float*)d_in[13];
  const float* bf1 = (const float*)d_in[14];
  const float* W2  = (const float*)d_in[15];
  const float* bf2 = (const float*)d_in[16];
  const float* g2  = (const float*)d_in[17];
  const float* be2 = (const float*)d_in[18];

  // workspace (short units); ~46.7 MB total. Aliases (stream-ordered safe):
  // att<-xb (xb dead after G1), h<-qk8/vh (dead after attn), f<-oproj (dead after LN1)
  unsigned short* xb    = (unsigned short*)d_ws;        // 4194304 (x f16)
  unsigned short* wqkvt = xb + 4194304;                 // 786432 (f16 B^T)
  unsigned short* wot   = wqkvt + 786432;               // 262144 (bf16)
  unsigned short* w1t   = wot + 262144;                 // 393216 (bf16)
  unsigned short* w2t   = w1t + 393216;                 // 393216 (bf16)
  signed char*    qk8   = (signed char*)(w2t + 393216); // 8192*1024 bytes
  unsigned short* vh    = (unsigned short*)(qk8 + 8388608); // 4194304 (v f16)
  unsigned short* oproj = vh + 4194304;                 // 4194304 (bf16)
  unsigned short* y     = oproj + 4194304;              // 4194304 (bf16)
  float*          maskb = (float*)(y + 4194304);        // 8192*32 f32
  unsigned short* att   = xb;
  unsigned short* h     = (unsigned short*)qk8;         // 8192*768 bf16 fits
  unsigned short* f     = oproj;

  k_prep<<<4864, 256, 0, stream>>>(adj, inx, maskb, x, xb, Wq, Wk, Wv, Wo, W1, W2,
                                   wqkvt, wot, w1t, w2t);

  // G1: [q8|k8|v_f16] = x @ [Wq|Wk|Wv] + b, 128x128 tile, 768 blocks
  k_gemm_qkv<<<768, 256, 0, stream>>>(xb, wqkvt, bq, bk, bv, qk8, vh);
  // attention (int8 scores, f16 PV)
  k_attn<<<2048, 256, 0, stream>>>(qk8, vh, maskb, inx, att);
  // G2: oproj = relu(att @ Wo + bo)
  k_gemm<1><<<512, 256, 0, stream>>>(att, wot, bo, oproj, 8192, 512, 512);
  // y = LN(x + oproj)
  k_ln1<<<2048, 256, 0, stream>>>(x, oproj, g1, be1, y);
  // G3: h = relu(y @ W1 + bf1)
  k_gemm<1><<<768, 256, 0, stream>>>(y, w1t, bf1, h, 8192, 768, 512);
  // G4: f = h @ W2 + bf2
  k_gemm<0><<<512, 256, 0, stream>>>(h, w2t, bf2, f, 8192, 512, 768);
  // out = LN(y + f)
  k_ln2<<<2048, 256, 0, stream>>>(y, f, g2, be2, (float*)d_out);
}